// Round 14
// baseline (309.945 us; speedup 1.0000x reference)
//
#include <hip/hip_runtime.h>
#include <hip/hip_fp16.h>
#include <stdint.h>

#define SEQ   2048
#define HID   4096
#define NH    32
#define NKV   8
#define KVDIM 1024   // NKV*HD
#define KVCAT 2048   // KVDIM*2

typedef int v4i __attribute__((ext_vector_type(4)));

#define VMCNT0 asm volatile("s_waitcnt vmcnt(0)" ::: "memory")

// async global->LDS 16B: per-lane global source, wave-uniform LDS base (+lane*16 by HW)
__device__ __forceinline__ void gload16(const void* g, void* l) {
    __builtin_amdgcn_global_load_lds(
        (const __attribute__((address_space(1))) void*)(uintptr_t)g,
        (__attribute__((address_space(3))) void*)(uintptr_t)l, 16, 0, 0);
}

// paired-row swizzle: 16B-chunk index for (row, c) in a [R][64] int8 tile
__device__ __forceinline__ int prsw(int row, int c) {
    return (row >> 1) * 8 + (row & 1) * 4 + (c ^ ((row >> 1) & 3));
}
// inverse: dest chunk d -> (row, c)
__device__ __forceinline__ void prsw_inv(int d, int& row, int& c) {
    int rp = d >> 3, rem = d & 7;
    row = 2 * rp + (rem >> 2);
    c = (rem & 3) ^ (rp & 3);
}

__device__ __forceinline__ float slot_scale(const unsigned* slots, int slot) {
    return fmaxf(__uint_as_float(slots[slot << 5]) / 127.0f, 1e-8f);
}

__device__ __forceinline__ int q8v(float x, float s) {
    int v = (int)rintf(x / s);
    return v < -127 ? -127 : (v > 127 ? 127 : v);
}

__device__ __forceinline__ unsigned pk4(float a, float b, float c, float d, float s) {
    return (unsigned)(uint8_t)(int8_t)q8v(a, s)
         | ((unsigned)(uint8_t)(int8_t)q8v(b, s) << 8)
         | ((unsigned)(uint8_t)(int8_t)q8v(c, s) << 16)
         | ((unsigned)(uint8_t)(int8_t)q8v(d, s) << 24);
}

__device__ __forceinline__ float fexp2(float x) {
    float r; asm("v_exp_f32 %0, %1" : "=v"(r) : "v"(x)); return r;
}

__device__ __forceinline__ float fmax4a(float4 x) {
    return fmaxf(fmaxf(fabsf(x.x), fabsf(x.y)), fmaxf(fabsf(x.z), fabsf(x.w)));
}

// block-level reduce (4 waves), ONE plain store (no atomic contention)
__device__ __forceinline__ void block_amax_part(float m, float* dst) {
    __shared__ float sm[4];
    int lane = threadIdx.x & 63, w = threadIdx.x >> 6;
    for (int off = 32; off; off >>= 1) m = fmaxf(m, __shfl_xor(m, off, 64));
    if (lane == 0) sm[w] = m;
    __syncthreads();
    if (threadIdx.x == 0)
        *dst = fmaxf(fmaxf(sm[0], sm[1]), fmaxf(sm[2], sm[3]));
    __syncthreads();
}

// ---------------- fused absmax: blocks partitioned per tensor ----------------
#define NV0 ((long)SEQ * HID / 4)     // 2M vecs
#define NV1 ((long)HID * HID / 4)     // 4M vecs
#define NV2 ((long)KVDIM * HID / 4)   // 1M vecs
__global__ void k_absmax5(const float* __restrict__ a0, const float* __restrict__ a1,
                          const float* __restrict__ a2, const float* __restrict__ a3,
                          const float* __restrict__ a4, float* __restrict__ part) {
    int b = blockIdx.x;
    const float* p; long n; int lb, nb;
    if (b < 342)       { p = a0; n = NV0; lb = b;        nb = 342; }
    else if (b < 1025) { p = a1; n = NV1; lb = b - 342;  nb = 683; }
    else if (b < 1196) { p = a2; n = NV2; lb = b - 1025; nb = 171; }
    else if (b < 1367) { p = a3; n = NV2; lb = b - 1196; nb = 171; }
    else               { p = a4; n = NV1; lb = b - 1367; nb = 681; }
    long str = (long)nb * 256;
    float mm[8] = {0.f, 0.f, 0.f, 0.f, 0.f, 0.f, 0.f, 0.f};
    long v = (long)lb * 256 + threadIdx.x;
    for (; v + 7 * str < n; v += 8 * str) {
        float4 t[8];
        #pragma unroll
        for (int j = 0; j < 8; j++) t[j] = *(const float4*)(p + (v + j * str) * 4);
        #pragma unroll
        for (int j = 0; j < 8; j++) mm[j] = fmaxf(mm[j], fmax4a(t[j]));
    }
    for (; v < n; v += str) mm[0] = fmaxf(mm[0], fmax4a(*(const float4*)(p + v * 4)));
    float m = fmaxf(fmaxf(fmaxf(mm[0], mm[1]), fmaxf(mm[2], mm[3])),
                    fmaxf(fmaxf(mm[4], mm[5]), fmaxf(mm[6], mm[7])));
    block_amax_part(m, part + blockIdx.x);
}

// ---------------- reduce partials -> slots 0..4 ----------------
__global__ void k_reduceA(const float* __restrict__ part, unsigned* slots) {
    __shared__ float sm[4];
    const int lo[5] = {0, 342, 1025, 1196, 1367};
    const int hi[5] = {342, 1025, 1196, 1367, 2048};
    int t = threadIdx.x, lane = t & 63, w = t >> 6;
    for (int s = 0; s < 5; s++) {
        float m = 0.f;
        for (int i = lo[s] + t; i < hi[s]; i += 256) m = fmaxf(m, part[i]);
        for (int off = 32; off; off >>= 1) m = fmaxf(m, __shfl_xor(m, off, 64));
        if (lane == 0) sm[w] = m;
        __syncthreads();
        if (t == 0)
            slots[s << 5] = __float_as_uint(fmaxf(fmaxf(sm[0], sm[1]), fmaxf(sm[2], sm[3])));
        __syncthreads();
    }
}

// ---------------- reduce partials -> slots 5 (q), 6 (k), 7 (v) ----------------
__global__ void k_reduceB(const float* __restrict__ p1, const float* __restrict__ p2,
                          const float* __restrict__ p3, unsigned* slots) {
    __shared__ float sm[4];
    int t = threadIdx.x, lane = t & 63, w = t >> 6;
    const float* ps[3] = {p1, p2, p3};
    const int cnt[3] = {512, 128, 128};
    const int sl[3] = {5, 6, 7};
    for (int s = 0; s < 3; s++) {
        float m = 0.f;
        for (int i = t; i < cnt[s]; i += 256) m = fmaxf(m, ps[s][i]);
        for (int off = 32; off; off >>= 1) m = fmaxf(m, __shfl_xor(m, off, 64));
        if (lane == 0) sm[w] = m;
        __syncthreads();
        if (t == 0)
            slots[sl[s] << 5] = __float_as_uint(fmaxf(fmaxf(sm[0], sm[1]), fmaxf(sm[2], sm[3])));
        __syncthreads();
    }
}

// ---------------- fused quantize of hid, wq, wk, wv, wo (16-elem units, packed) --------
#define NU0 ((long)SEQ * HID / 16)
#define NU1 ((long)HID * HID / 16)
#define NU2 ((long)KVDIM * HID / 16)
__global__ void k_quant5(const float* __restrict__ a0, const float* __restrict__ a1,
                         const float* __restrict__ a2, const float* __restrict__ a3,
                         const float* __restrict__ a4,
                         int8_t* __restrict__ d0, int8_t* __restrict__ d1,
                         int8_t* __restrict__ d2, int8_t* __restrict__ d3,
                         int8_t* __restrict__ d4,
                         const unsigned* __restrict__ slots) {
    int b = blockIdx.x;
    const float* p; int8_t* d; long n; int slot, lb, nb;
    if (b < 512)       { p = a0; d = d0; n = NU0; slot = 0; lb = b;        nb = 512; }
    else if (b < 1536) { p = a1; d = d1; n = NU1; slot = 1; lb = b - 512;  nb = 1024; }
    else if (b < 1792) { p = a2; d = d2; n = NU2; slot = 2; lb = b - 1536; nb = 256; }
    else if (b < 2048) { p = a3; d = d3; n = NU2; slot = 3; lb = b - 1792; nb = 256; }
    else               { p = a4; d = d4; n = NU1; slot = 4; lb = b - 2048; nb = 512; }
    float s = slot_scale(slots, slot);
    long str = (long)nb * 256;
    for (long u = (long)lb * 256 + threadIdx.x; u < n; u += str) {
        const float4* src = (const float4*)(p + u * 16);
        float4 t0 = src[0], t1 = src[1], t2 = src[2], t3 = src[3];
        int4 o;
        o.x = (int)pk4(t0.x, t0.y, t0.z, t0.w, s);
        o.y = (int)pk4(t1.x, t1.y, t1.z, t1.w, s);
        o.z = (int)pk4(t2.x, t2.y, t2.z, t2.w, s);
        o.w = (int)pk4(t3.x, t3.y, t3.z, t3.w, s);
        *(int4*)(d + u * 16) = o;
    }
}

// ---------------- f16 -> int8 (16-half units; strided-capable), packed ----------------
__device__ __forceinline__ unsigned pk4h(unsigned h2a, unsigned h2b, float s) {
    __half2 a = *(__half2*)&h2a, b = *(__half2*)&h2b;
    return pk4(__low2float(a), __high2float(a), __low2float(b), __high2float(b), s);
}
__global__ void k_quanth(const __half* __restrict__ x, int8_t* __restrict__ q, long nu,
                         int rshift, long cmask, long ld,
                         const unsigned* __restrict__ slots, int slot) {
    float s = slot_scale(slots, slot);
    long gs = (long)gridDim.x * blockDim.x;
    for (long u = blockIdx.x * (long)blockDim.x + threadIdx.x; u < nu; u += gs) {
        long row = u >> rshift;
        long cu = u & cmask;
        const int4* src = (const int4*)(x + row * ld + cu * 16);
        int4 a = src[0], b = src[1];
        int4 o;
        o.x = (int)pk4h((unsigned)a.x, (unsigned)a.y, s);
        o.y = (int)pk4h((unsigned)a.z, (unsigned)a.w, s);
        o.z = (int)pk4h((unsigned)b.x, (unsigned)b.y, s);
        o.w = (int)pk4h((unsigned)b.z, (unsigned)b.w, s);
        *(int4*)(q + u * 16) = o;
    }
}

// ---------------- rope cos/sin table ----------------
__global__ void k_ropetab(const int* __restrict__ pos, float* __restrict__ ct,
                          float* __restrict__ st) {
    int tid = blockIdx.x * blockDim.x + threadIdx.x;
    if (tid >= SEQ * 64) return;
    int i = tid & 63, s = tid >> 6;
    double inv = 1.0 / pow(10000.0, (double)((float)(2 * i) * (1.0f / 128.0f)));
    float invf = (float)inv;
    float angf = (float)pos[s] * invf;
    double a = (double)angf;
    ct[tid] = (float)cos(a);
    st[tid] = (float)sin(a);
}

// ---------------- transpose + quantize (V f16 -> V^T int8) ----------------
__global__ void k_transq(const __half* __restrict__ src, long lds_, int8_t* __restrict__ dst,
                         long ldd, const unsigned* __restrict__ slots, int slot) {
    __shared__ float t[32][33];
    float s = slot_scale(slots, slot);
    int bx = blockIdx.x, by = blockIdx.y;
    int tid = threadIdx.x;
    int c = tid & 31, r0 = tid >> 5;
    #pragma unroll
    for (int j = 0; j < 4; j++) {
        int r = r0 + j * 8;
        t[r][c] = __half2float(src[(long)(by * 32 + r) * lds_ + bx * 32 + c]);
    }
    __syncthreads();
    int d = tid >> 3, k4 = (tid & 7) * 4;
    unsigned pa = 0;
    #pragma unroll
    for (int j = 0; j < 4; j++) {
        int iv = q8v(t[k4 + j][d], s);
        pa |= ((unsigned)(uint8_t)(int8_t)iv) << (8 * j);
    }
    *(unsigned*)(dst + (long)(bx * 32 + d) * ldd + by * 32 + k4) = pa;
}

// ---------------- int8 GEMM 128x128, BK=64, paired-row swizzle, 32KB LDS ----------------
// ropemode: 0 = plain f32 store; 1 = rope all cols (Q, f16 out), partial->pQ[blockIdx];
//           2 = KV f16 out: bn<8 rope (K)->pK, bn>=8 absmax (V)->pV
__global__ __launch_bounds__(256) void k_gemm_i8(
    const int8_t* __restrict__ A, const int8_t* __restrict__ B, void* __restrict__ Cv,
    int N, int K, unsigned* slots,
    int slotA, int slotB, int slotB2, int nsplit,
    float* pQ, float* pK, float* pV, int ropemode,
    const float* __restrict__ ct, const float* __restrict__ st) {
    __shared__ int8_t POOL[32768];
    int8_t (*As)[8192] = (int8_t(*)[8192])POOL;
    int8_t (*Bs)[8192] = (int8_t(*)[8192])(POOL + 16384);
    float* Cf = (float*)Cv;
    __half* Ch = (__half*)Cv;
    const v4i vzero = {0, 0, 0, 0};
    int tid = threadIdx.x, lane = tid & 63, wid = tid >> 6;
    int qlan = lane & 15, g = lane >> 4;
    int nbx = N >> 7;
    int nwg = gridDim.x, wg = blockIdx.x;
    int cpx = nwg >> 3;
    int swz = (wg & 7) * cpx + (wg >> 3);
    int bm = swz / nbx, bn = swz % nbx;
    long rowA0 = (long)bm * 128, colB0 = (long)bn * 128;
    int wrow = (wid >> 1) * 64, wcol = (wid & 1) * 64;
    // per-thread staging sources (chunk d = tid, tid+256), paired-row inverse on source
    int r0_, c0_, r1_, c1_;
    prsw_inv(tid, r0_, c0_);
    prsw_inv(tid + 256, r1_, c1_);
    const int8_t* sA0 = A + (rowA0 + r0_) * (long)K + c0_ * 16;
    const int8_t* sA1 = A + (rowA0 + r1_) * (long)K + c1_ * 16;
    const int8_t* sB0 = B + (colB0 + r0_) * (long)K + c0_ * 16;
    const int8_t* sB1 = B + (colB0 + r1_) * (long)K + c1_ * 16;
    v4i acc[4][4];
    #pragma unroll
    for (int m = 0; m < 4; m++)
        #pragma unroll
        for (int n = 0; n < 4; n++) acc[m][n] = vzero;
    // precompute frag LDS offsets (loop-invariant)
    int aoff[4], boff[4];
    #pragma unroll
    for (int m = 0; m < 4; m++) {
        int row = wrow + m * 16 + qlan;
        aoff[m] = prsw(row, g) * 16;
        int rowb = wcol + m * 16 + qlan;
        boff[m] = prsw(rowb, g) * 16;
    }

    auto STAGE = [&](int buf, int kt) {
        gload16(sA0 + kt, &As[buf][wid * 1024]);
        gload16(sA1 + kt, &As[buf][wid * 1024 + 4096]);
        gload16(sB0 + kt, &Bs[buf][wid * 1024]);
        gload16(sB1 + kt, &Bs[buf][wid * 1024 + 4096]);
    };
    auto COMPUTE = [&](int buf) {
        v4i af[4], bf[4];
        #pragma unroll
        for (int m = 0; m < 4; m++) af[m] = *(const v4i*)(&As[buf][aoff[m]]);
        #pragma unroll
        for (int n = 0; n < 4; n++) bf[n] = *(const v4i*)(&Bs[buf][boff[n]]);
        #pragma unroll
        for (int m = 0; m < 4; m++)
            #pragma unroll
            for (int n = 0; n < 4; n++)
                acc[m][n] = __builtin_amdgcn_mfma_i32_16x16x64_i8(af[m], bf[n], acc[m][n], 0, 0, 0);
    };

    STAGE(0, 0);
    VMCNT0;
    __syncthreads();
    int nt = K >> 6, cur = 0;
    for (int t = 0; t < nt - 1; t++) {
        STAGE(cur ^ 1, (t + 1) << 6);
        COMPUTE(cur);
        VMCNT0;
        __syncthreads();
        cur ^= 1;
    }
    COMPUTE(cur);

    float sA = slot_scale(slots, slotA);
    float sB1s = slot_scale(slots, slotB);
    float sB2s = slot_scale(slots, slotB2);
    int qc = qlan, rgrp = g << 2;
    if (ropemode == 1 || (ropemode == 2 && bn < 8)) {
        __syncthreads();                      // As/Bs dead for all waves
        __half* EXh = (__half*)POOL;          // 128x128 f16, XOR-swizzled (32KB)
        #pragma unroll
        for (int m = 0; m < 4; m++)
            #pragma unroll
            for (int n = 0; n < 4; n++) {
                int coll = wcol + n * 16 + qc;
                #pragma unroll
                for (int r = 0; r < 4; r++) {
                    int rowl = wrow + m * 16 + rgrp + r;
                    EXh[rowl * 128 + (coll ^ ((rowl & 1) << 4))] =
                        __float2half(sA * sB1s * (float)acc[m][n][r]);
                }
            }
        __syncthreads();
        float am = 0.f;
        #pragma unroll
        for (int m = 0; m < 4; m++)
            #pragma unroll
            for (int n = 0; n < 4; n++) {
                int coll = wcol + n * 16 + qc;
                #pragma unroll
                for (int r = 0; r < 4; r++) {
                    int rowl = wrow + m * 16 + rgrp + r;
                    long srow = rowA0 + rowl;
                    float self = __half2float(EXh[rowl * 128 + (coll ^ ((rowl & 1) << 4))]);
                    float pv = __half2float(EXh[rowl * 128 + ((coll ^ 64) ^ ((rowl & 1) << 4))]);
                    float c = ct[srow * 64 + (coll & 63)];
                    float sn = st[srow * 64 + (coll & 63)];
                    float o = (coll < 64) ? self * c - pv * sn : self * c + pv * sn;
                    am = fmaxf(am, fabsf(o));
                    Ch[srow * N + colB0 + coll] = __float2half(o);
                }
            }
        block_amax_part(am, (ropemode == 1) ? pQ + blockIdx.x : pK + bm * 8 + (bn & 7));
    } else if (ropemode == 2) {               // V tile: scale + f16 store + absmax
        float am = 0.f;
        #pragma unroll
        for (int m = 0; m < 4; m++) {
            long row0 = rowA0 + wrow + m * 16 + rgrp;
            #pragma unroll
            for (int n = 0; n < 4; n++) {
                int col = (int)colB0 + wcol + n * 16 + qc;
                float sc = sA * ((col < nsplit) ? sB1s : sB2s);
                __half* cp = Ch + row0 * N + col;
                #pragma unroll
                for (int r = 0; r < 4; r++) {
                    float val = sc * (float)acc[m][n][r];
                    cp[(long)r * N] = __float2half(val);
                    am = fmaxf(am, fabsf(val));
                }
            }
        }
        block_amax_part(am, pV + bm * 8 + (bn & 7));
    } else {
        #pragma unroll
        for (int m = 0; m < 4; m++) {
            long row0 = rowA0 + wrow + m * 16 + rgrp;
            #pragma unroll
            for (int n = 0; n < 4; n++) {
                int col = (int)colB0 + wcol + n * 16 + qc;
                float sc = sA * ((col < nsplit) ? sB1s : sB2s);
                float* cp = Cf + row0 * N + col;
                #pragma unroll
                for (int r = 0; r < 4; r++) cp[(long)r * N] = sc * (float)acc[m][n][r];
            }
        }
    }
}

// ---------------- two-pass flash attention (fused-exp softmax, 37.9KB LDS) --------------
__global__ __launch_bounds__(256) void k_attn(
    const int8_t* __restrict__ Qq, const int8_t* __restrict__ Kq, const int8_t* __restrict__ Vtq,
    __half* __restrict__ AO, unsigned* slots) {
    __shared__ int8_t Ks[2][64 * 128];
    __shared__ int8_t Vs[2][128 * 64];   // paired-row swizzled; [0] doubles as Q staging
    __shared__ unsigned Ps[4 * 320];     // packed-P (20-dword stride per warp)
    __shared__ int smx[4];
    const v4i vzero = {0, 0, 0, 0};
    const int NEGS = -(1 << 29);
    const float MAGIC = 12582912.0f;  // 1.5*2^23, RNE rounding
    int tid = threadIdx.x, lane = tid & 63, w = tid >> 6;
    int qlan = lane & 15, g = lane >> 4;
    int idx = blockIdx.x;
    int qb = 31 - (idx >> 5), h = idx & 31, kvh = h >> 2;   // long blocks first
    float sq = slot_scale(slots, 5), sk = slot_scale(slots, 6);
    float spv = slot_scale(slots, 7) * (1.0f / 127.0f);
    float c2 = sq * sk * 0.08838834764831845f * 1.4426950408889634f;
    int lr8 = lane >> 3;
    int swc = ((lane & 7) ^ lr8) * 16;
    const int8_t* kbase = Kq + ((long)(w * 8 + lr8)) * KVDIM + kvh * 128 + swc;
    // V staging: per-thread paired-row inverse source (chunks tid, tid+256)
    int vr0_, vc0_, vr1_, vc1_;
    prsw_inv(tid, vr0_, vc0_);
    prsw_inv(tid + 256, vr1_, vc1_);
    const int8_t* sV0 = Vtq + ((long)kvh * 128 + vr0_) * SEQ + vc0_ * 16;
    const int8_t* sV1 = Vtq + ((long)kvh * 128 + vr1_) * SEQ + vc1_ * 16;
    auto STAGE_K = [&](int buf, int kt) {
        #pragma unroll
        for (int i = 0; i < 2; i++)
            gload16(kbase + ((long)kt * 64 + i * 32) * KVDIM, &Ks[buf][(w * 8 + i * 32) * 128]);
    };
    auto STAGE_V = [&](int buf, int kt) {
        gload16(sV0 + kt * 64, &Vs[buf][w * 1024]);
        gload16(sV1 + kt * 64, &Vs[buf][w * 1024 + 4096]);
    };
    // stage Q (64x128, row&7 XOR layout) into Vs space (dead until pass 2)
    {
        int8_t* Qstage = &Vs[0][0];
        const int8_t* qbase = Qq + ((long)qb * 64 + w * 8 + lr8) * HID + h * 128 + swc;
        #pragma unroll
        for (int i = 0; i < 2; i++)
            gload16(qbase + (long)(i * 32) * HID, &Qstage[(w * 8 + i * 32) * 128]);
    }
    STAGE_K(0, 0);
    VMCNT0;
    __syncthreads();
    v4i aq[2];
    #pragma unroll
    for (int ks = 0; ks < 2; ks++) {
        int row = w * 16 + qlan;
        aq[ks] = *(const v4i*)(&Vs[0][row * 128 + (((ks * 4 + g) ^ (row & 7)) * 16)]);
    }
    __syncthreads();   // all aq reads done before Vs reuse
    int mi = -(1 << 30);
    float l = 0.f;
    int buf = 0;
    // ---- pass 1: int row-max + fused-exp denominator ----
    for (int kt = 0; kt <= qb; kt++) {
        if (kt < qb) STAGE_K(buf ^ 1, kt + 1);
        v4i sf[4] = {vzero, vzero, vzero, vzero};
        __builtin_amdgcn_s_setprio(1);
        #pragma unroll
        for (int ks = 0; ks < 2; ks++)
            #pragma unroll
            for (int f = 0; f < 4; f++) {
                int row = f * 16 + qlan;
                v4i bk = *(const v4i*)(&Ks[buf][row * 128 + (((ks * 4 + g) ^ (row & 7)) * 16)]);
                sf[f] = __builtin_amdgcn_mfma_i32_16x16x64_i8(bk, aq[ks], sf[f], 0, 0, 0);
            }
        __builtin_amdgcn_s_setprio(0);
        int sv[16];
        if (kt == qb) {
            int qthr = w * 16 + qlan;
            #pragma unroll
            for (int f = 0; f < 4; f++)
                #pragma unroll
                for (int r = 0; r < 4; r++) {
                    int kl = f * 16 + g * 4 + r;
                    sv[f * 4 + r] = (kl > qthr) ? NEGS : sf[f][r];
                }
        } else {
            #pragma unroll
            for (int f = 0; f < 4; f++)
                #pragma unroll
                for (int r = 0; r < 4; r++) sv[f * 4 + r] = sf[f][r];
        }
        int tm = sv[0];
        #pragma unroll
        for (int e = 1; e < 16; e++) tm = tm > sv[e] ? tm : sv[e];
        tm = max(tm, __shfl_xor(tm, 16, 64));
        tm = max(tm, __shfl_xor(tm, 32, 64));
        int mn = tm > mi ? tm : mi;
        float nb = -c2 * (float)mn;
        float esc = fexp2(fmaf((float)mi, c2, nb));
        float es = 0.f;
        #pragma unroll
        for (int e = 0; e < 16; e++) es += fexp2(fmaf((float)sv[e], c2, nb));
        es += __shfl_xor(es, 16, 64);
        es += __shfl_xor(es, 32, 64);
        l = l * esc + es;
        mi = mn;
        VMCNT0;
        __syncthreads();
        buf ^= 1;
    }
    // fused quant bias: p_q127 = exp2(c2*s - Bq), Bq = c2*m + log2(l) - log2(127)
    float Bq = fmaf(c2, (float)mi, __log2f(l) - 6.9886846867721655f);
    // ---- pass 2 ----
    int pwr = w * 320;
    v4i of[8];
    #pragma unroll
    for (int nf = 0; nf < 8; nf++) of[nf] = vzero;
    STAGE_K(0, 0);
    STAGE_V(0, 0);
    VMCNT0;
    __syncthreads();
    buf = 0;
    for (int kt = 0; kt <= qb; kt++) {
        if (kt < qb) { STAGE_K(buf ^ 1, kt + 1); STAGE_V(buf ^ 1, kt + 1); }
        v4i sf[4] = {vzero, vzero, vzero, vzero};
        __builtin_amdgcn_s_setprio(1);
        #pragma unroll
        for (int ks = 0; ks < 2; ks++)
            #pragma unroll
            for (int f = 0; f < 4; f++) {
                int row = f * 16 + qlan;
                v4i bk = *(const v4i*)(&Ks[buf][row * 128 + (((ks * 4 + g) ^ (row & 7)) * 16)]);
                sf[f] = __builtin_amdgcn_mfma_i32_16x16x64_i8(bk, aq[ks], sf[f], 0, 0, 0);
            }
        __builtin_amdgcn_s_setprio(0);
        if (kt == qb) {
            int qthr = w * 16 + qlan;
            #pragma unroll
            for (int f = 0; f < 4; f++) {
                unsigned pk = 0;
                #pragma unroll
                for (int r = 0; r < 4; r++) {
                    int kl = f * 16 + g * 4 + r;
                    int s = (kl > qthr) ? NEGS : sf[f][r];
                    float t = fexp2(fmaf((float)s, c2, -Bq));
                    unsigned u = __float_as_uint(t + MAGIC) & 127u;
                    pk |= u << (8 * r);
                }
                Ps[pwr + (4 * f + g) * 20 + qlan] = pk;
            }
        } else {
            #pragma unroll
            for (int f = 0; f < 4; f++) {
                unsigned pk = 0;
                #pragma unroll
                for (int r = 0; r < 4; r++) {
                    float t = fexp2(fmaf((float)sf[f][r], c2, -Bq));
                    unsigned u = __float_as_uint(t + MAGIC) & 127u;
                    pk |= u << (8 * r);
                }
                Ps[pwr + (4 * f + g) * 20 + qlan] = pk;
            }
        }
        int rb = pwr + 80 * g + qlan;
        v4i ap;
        ap[0] = (int)Ps[rb];
        ap[1] = (int)Ps[rb + 20];
        ap[2] = (int)Ps[rb + 40];
        ap[3] = (int)Ps[rb + 60];
        __builtin_amdgcn_s_setprio(1);
        #pragma unroll
        for (int nf = 0; nf < 8; nf++) {
            int row = nf * 16 + qlan;
            v4i bv = *(const v4i*)(&Vs[buf][prsw(row, g) * 16]);
            of[nf] = __builtin_amdgcn_mfma_i32_16x16x64_i8(ap, bv, of[nf], 0, 0, 0);
        }
        __builtin_amdgcn_s_setprio(0);
        VMCNT0;
        __syncthreads();
        buf ^= 1;
    }
    int mymax = 0;
    #pragma unroll
    for (int nf = 0; nf < 8; nf++)
        #pragma unroll
        for (int r = 0; r < 4; r++) {
            int val = of[nf][r];
            int av = val < 0 ? -val : val;
            mymax = av > mymax ? av : mymax;
            int qg = qb * 64 + w * 16 + 4 * g + r;
            AO[(long)qg * HID + h * 128 + nf * 16 + qlan] = __float2half(spv * (float)val);
        }
    #pragma unroll
    for (int off = 1; off < 64; off <<= 1) {
        int o2 = __shfl_xor(mymax, off, 64);
        mymax = o2 > mymax ? o2 : mymax;
    }
    if (lane == 0) smx[w] = mymax;
    __syncthreads();
    if (tid == 0) {
        int mm = max(max(smx[0], smx[1]), max(smx[2], smx[3]));
        atomicMax(slots + (8 << 5), (unsigned)mm);   // staggered retirement
    }
}

// ---------------- quantize attn_out (f16 -> int8), packed ----------------
__global__ void k_quant_ao(const __half* __restrict__ a, int8_t* __restrict__ q,
                           unsigned* slots) {
    float sv = slot_scale(slots, 7);
    float spv = (1.0f / 127.0f) * sv;
    float amax = spv * (float)(int)slots[8 << 5];
    float s = fmaxf(amax / 127.0f, 1e-8f);
    long nu = (long)SEQ * HID / 16;
    long gs = (long)gridDim.x * blockDim.x;
    for (long u = blockIdx.x * (long)blockDim.x + threadIdx.x; u < nu; u += gs) {
        const int4* src = (const int4*)(a + u * 16);
        int4 x = src[0], y = src[1];
        int4 o;
        o.x = (int)pk4h((unsigned)x.x, (unsigned)x.y, s);
        o.y = (int)pk4h((unsigned)x.z, (unsigned)x.w, s);
        o.z = (int)pk4h((unsigned)y.x, (unsigned)y.y, s);
        o.w = (int)pk4h((unsigned)y.z, (unsigned)y.w, s);
        *(int4*)(q + u * 16) = o;
    }
    if (blockIdx.x == 0 && threadIdx.x == 0) slots[9 << 5] = __float_as_uint(amax);
}

extern "C" void kernel_launch(void* const* d_in, const int* in_sizes, int n_in,
                              void* d_out, int out_size, void* d_ws, size_t ws_size,
                              hipStream_t stream) {
    (void)in_sizes; (void)n_in; (void)out_size;
    const float* hid = (const float*)d_in[0];
    const int* pos = (const int*)d_in[2];
    const float* wqp = (const float*)d_in[3];
    const float* wkp = (const float*)d_in[4];
    const float* wvp = (const float*)d_in[5];
    const float* wop = (const float*)d_in[6];
    float* out = (float*)d_out;
    char* ws = (char*)d_ws;

    size_t o = 0;
    auto alloc = [&](size_t sz) { size_t r = o; o += (sz + 255) & ~(size_t)255; return r; };
    unsigned* slots = (unsigned*)(ws + alloc(2048));
    float* P0 = (float*)(ws + alloc(2048 * 4));      // absmax5 partials
    float* P1 = (float*)(ws + alloc(512 * 4));       // gemm1 Q-rope partials
    float* P2 = (float*)(ws + alloc(128 * 4));       // gemm2 K-rope partials
    float* P3 = (float*)(ws + alloc(128 * 4));       // gemm2 V partials
    int8_t* Xq   = (int8_t*)(ws + alloc((size_t)SEQ * HID));      // later reused as AOq
    int8_t* Wqq  = (int8_t*)(ws + alloc((size_t)HID * HID));
    int8_t* Woq  = (int8_t*)(ws + alloc((size_t)HID * HID));
    int8_t* Wkvq = (int8_t*)(ws + alloc((size_t)KVCAT * HID));
    __half* Qf   = (__half*)(ws + alloc((size_t)SEQ * HID * 2));  // later reused as AOh
    __half* KVf  = (__half*)(ws + alloc((size_t)SEQ * KVCAT * 2));
    int8_t* Qq   = (int8_t*)(ws + alloc((size_t)SEQ * HID));
    int8_t* Kq   = (int8_t*)(ws + alloc((size_t)SEQ * KVDIM));
    int8_t* Vtq  = (int8_t*)(ws + alloc((size_t)KVDIM * SEQ));
    float*  ctab = (float*)(ws + alloc((size_t)SEQ * 64 * 4));
    float*  stab = (float*)(ws + alloc((size_t)SEQ * 64 * 4));
    if (ws_size < o) return;
    __half* AOh = Qf;
    int8_t* AOq = Xq;

    (void)hipMemsetAsync(slots, 0, 2048, stream);
    k_ropetab<<<SEQ * 64 / 256, 256, 0, stream>>>(pos, ctab, stab);
    k_absmax5<<<2048, 256, 0, stream>>>(hid, wqp, wkp, wvp, wop, P0);
    k_reduceA<<<1, 256, 0, stream>>>(P0, slots);
    k_quant5<<<2560, 256, 0, stream>>>(hid, wqp, wkp, wvp, wop,
                                       Xq, Wqq, Wkvq, Wkvq + (size_t)KVDIM * HID, Woq, slots);
    k_gemm_i8<<<512, 256, 0, stream>>>(Xq, Wqq, Qf, HID, HID, slots,
                                       0, 1, 1, 1 << 30, P1, nullptr, nullptr, 1, ctab, stab);
    k_gemm_i8<<<256, 256, 0, stream>>>(Xq, Wkvq, KVf, KVCAT, HID, slots,
                                       0, 2, 3, KVDIM, nullptr, P2, P3, 2, ctab, stab);
    k_reduceB<<<1, 256, 0, stream>>>(P1, P2, P3, slots);
    const long CALL = 0x3FFFFFFFL;
    k_quanth<<<1024, 256, 0, stream>>>(Qf, Qq, (long)SEQ * HID / 16, 40, CALL, 0, slots, 5);
    k_quanth<<<512, 256, 0, stream>>>(KVf, Kq, (long)SEQ * KVDIM / 16, 6, 63, KVCAT, slots, 6);
    k_transq<<<dim3(32, 64), 256, 0, stream>>>(KVf + KVDIM, KVCAT, Vtq, SEQ, slots, 7);
    k_attn<<<1024, 256, 0, stream>>>(Qq, Kq, Vtq, AOh, slots);
    k_quant_ao<<<1024, 256, 0, stream>>>(AOh, AOq, slots);
    k_gemm_i8<<<512, 256, 0, stream>>>(AOq, Woq, out, HID, HID, slots,
                                       9, 4, 4, 1 << 30, nullptr, nullptr, nullptr, 0,
                                       nullptr, nullptr);
}

// Round 15
// 290.034 us; speedup vs baseline: 1.0687x; 1.0687x over previous
//
#include <hip/hip_runtime.h>
#include <hip/hip_fp16.h>
#include <stdint.h>

#define SEQ   2048
#define HID   4096
#define NH    32
#define NKV   8
#define KVDIM 1024   // NKV*HD
#define KVCAT 2048   // KVDIM*2

typedef int v4i __attribute__((ext_vector_type(4)));

#define VMCNT0 asm volatile("s_waitcnt vmcnt(0)" ::: "memory")

// async global->LDS 16B: per-lane global source, wave-uniform LDS base (+lane*16 by HW)
__device__ __forceinline__ void gload16(const void* g, void* l) {
    __builtin_amdgcn_global_load_lds(
        (const __attribute__((address_space(1))) void*)(uintptr_t)g,
        (__attribute__((address_space(3))) void*)(uintptr_t)l, 16, 0, 0);
}

// paired-row swizzle: 16B-chunk index for (row, c) in a [R][64] int8 tile
__device__ __forceinline__ int prsw(int row, int c) {
    return (row >> 1) * 8 + (row & 1) * 4 + (c ^ ((row >> 1) & 3));
}
// inverse: dest chunk d -> (row, c)
__device__ __forceinline__ void prsw_inv(int d, int& row, int& c) {
    int rp = d >> 3, rem = d & 7;
    row = 2 * rp + (rem >> 2);
    c = (rem & 3) ^ (rp & 3);
}

__device__ __forceinline__ float slot_scale(const unsigned* slots, int slot) {
    return fmaxf(__uint_as_float(slots[slot << 5]) / 127.0f, 1e-8f);
}

__device__ __forceinline__ int q8v(float x, float s) {
    int v = (int)rintf(x / s);
    return v < -127 ? -127 : (v > 127 ? 127 : v);
}

__device__ __forceinline__ unsigned pk4(float a, float b, float c, float d, float s) {
    return (unsigned)(uint8_t)(int8_t)q8v(a, s)
         | ((unsigned)(uint8_t)(int8_t)q8v(b, s) << 8)
         | ((unsigned)(uint8_t)(int8_t)q8v(c, s) << 16)
         | ((unsigned)(uint8_t)(int8_t)q8v(d, s) << 24);
}

__device__ __forceinline__ float fexp2(float x) {
    float r; asm("v_exp_f32 %0, %1" : "=v"(r) : "v"(x)); return r;
}

__device__ __forceinline__ float fmax4a(float4 x) {
    return fmaxf(fmaxf(fabsf(x.x), fabsf(x.y)), fmaxf(fabsf(x.z), fabsf(x.w)));
}

// block-level reduce (4 waves), ONE plain store (no atomic contention)
__device__ __forceinline__ void block_amax_part(float m, float* dst) {
    __shared__ float sm[4];
    int lane = threadIdx.x & 63, w = threadIdx.x >> 6;
    for (int off = 32; off; off >>= 1) m = fmaxf(m, __shfl_xor(m, off, 64));
    if (lane == 0) sm[w] = m;
    __syncthreads();
    if (threadIdx.x == 0)
        *dst = fmaxf(fmaxf(sm[0], sm[1]), fmaxf(sm[2], sm[3]));
    __syncthreads();
}

// ---------------- fused absmax: blocks partitioned per tensor ----------------
#define NV0 ((long)SEQ * HID / 4)     // 2M vecs
#define NV1 ((long)HID * HID / 4)     // 4M vecs
#define NV2 ((long)KVDIM * HID / 4)   // 1M vecs
__global__ void k_absmax5(const float* __restrict__ a0, const float* __restrict__ a1,
                          const float* __restrict__ a2, const float* __restrict__ a3,
                          const float* __restrict__ a4, float* __restrict__ part) {
    int b = blockIdx.x;
    const float* p; long n; int lb, nb;
    if (b < 342)       { p = a0; n = NV0; lb = b;        nb = 342; }
    else if (b < 1025) { p = a1; n = NV1; lb = b - 342;  nb = 683; }
    else if (b < 1196) { p = a2; n = NV2; lb = b - 1025; nb = 171; }
    else if (b < 1367) { p = a3; n = NV2; lb = b - 1196; nb = 171; }
    else               { p = a4; n = NV1; lb = b - 1367; nb = 681; }
    long str = (long)nb * 256;
    float mm[8] = {0.f, 0.f, 0.f, 0.f, 0.f, 0.f, 0.f, 0.f};
    long v = (long)lb * 256 + threadIdx.x;
    for (; v + 7 * str < n; v += 8 * str) {
        float4 t[8];
        #pragma unroll
        for (int j = 0; j < 8; j++) t[j] = *(const float4*)(p + (v + j * str) * 4);
        #pragma unroll
        for (int j = 0; j < 8; j++) mm[j] = fmaxf(mm[j], fmax4a(t[j]));
    }
    for (; v < n; v += str) mm[0] = fmaxf(mm[0], fmax4a(*(const float4*)(p + v * 4)));
    float m = fmaxf(fmaxf(fmaxf(mm[0], mm[1]), fmaxf(mm[2], mm[3])),
                    fmaxf(fmaxf(mm[4], mm[5]), fmaxf(mm[6], mm[7])));
    block_amax_part(m, part + blockIdx.x);
}

// ---------------- reduce partials -> slots 0..4 ----------------
__global__ void k_reduceA(const float* __restrict__ part, unsigned* slots) {
    __shared__ float sm[4];
    const int lo[5] = {0, 342, 1025, 1196, 1367};
    const int hi[5] = {342, 1025, 1196, 1367, 2048};
    int t = threadIdx.x, lane = t & 63, w = t >> 6;
    for (int s = 0; s < 5; s++) {
        float m = 0.f;
        for (int i = lo[s] + t; i < hi[s]; i += 256) m = fmaxf(m, part[i]);
        for (int off = 32; off; off >>= 1) m = fmaxf(m, __shfl_xor(m, off, 64));
        if (lane == 0) sm[w] = m;
        __syncthreads();
        if (t == 0)
            slots[s << 5] = __float_as_uint(fmaxf(fmaxf(sm[0], sm[1]), fmaxf(sm[2], sm[3])));
        __syncthreads();
    }
}

// ---------------- reduce partials -> slots 5 (q), 6 (k), 7 (v) ----------------
__global__ void k_reduceB(const float* __restrict__ p1, const float* __restrict__ p2,
                          const float* __restrict__ p3, unsigned* slots) {
    __shared__ float sm[4];
    int t = threadIdx.x, lane = t & 63, w = t >> 6;
    const float* ps[3] = {p1, p2, p3};
    const int cnt[3] = {512, 128, 128};
    const int sl[3] = {5, 6, 7};
    for (int s = 0; s < 3; s++) {
        float m = 0.f;
        for (int i = t; i < cnt[s]; i += 256) m = fmaxf(m, ps[s][i]);
        for (int off = 32; off; off >>= 1) m = fmaxf(m, __shfl_xor(m, off, 64));
        if (lane == 0) sm[w] = m;
        __syncthreads();
        if (t == 0)
            slots[sl[s] << 5] = __float_as_uint(fmaxf(fmaxf(sm[0], sm[1]), fmaxf(sm[2], sm[3])));
        __syncthreads();
    }
}

// ---------------- fused quantize of hid, wq, wk, wv, wo (16-elem units, packed) --------
#define NU0 ((long)SEQ * HID / 16)
#define NU1 ((long)HID * HID / 16)
#define NU2 ((long)KVDIM * HID / 16)
__global__ void k_quant5(const float* __restrict__ a0, const float* __restrict__ a1,
                         const float* __restrict__ a2, const float* __restrict__ a3,
                         const float* __restrict__ a4,
                         int8_t* __restrict__ d0, int8_t* __restrict__ d1,
                         int8_t* __restrict__ d2, int8_t* __restrict__ d3,
                         int8_t* __restrict__ d4,
                         const unsigned* __restrict__ slots) {
    int b = blockIdx.x;
    const float* p; int8_t* d; long n; int slot, lb, nb;
    if (b < 512)       { p = a0; d = d0; n = NU0; slot = 0; lb = b;        nb = 512; }
    else if (b < 1536) { p = a1; d = d1; n = NU1; slot = 1; lb = b - 512;  nb = 1024; }
    else if (b < 1792) { p = a2; d = d2; n = NU2; slot = 2; lb = b - 1536; nb = 256; }
    else if (b < 2048) { p = a3; d = d3; n = NU2; slot = 3; lb = b - 1792; nb = 256; }
    else               { p = a4; d = d4; n = NU1; slot = 4; lb = b - 2048; nb = 512; }
    float s = slot_scale(slots, slot);
    long str = (long)nb * 256;
    for (long u = (long)lb * 256 + threadIdx.x; u < n; u += str) {
        const float4* src = (const float4*)(p + u * 16);
        float4 t0 = src[0], t1 = src[1], t2 = src[2], t3 = src[3];
        int4 o;
        o.x = (int)pk4(t0.x, t0.y, t0.z, t0.w, s);
        o.y = (int)pk4(t1.x, t1.y, t1.z, t1.w, s);
        o.z = (int)pk4(t2.x, t2.y, t2.z, t2.w, s);
        o.w = (int)pk4(t3.x, t3.y, t3.z, t3.w, s);
        *(int4*)(d + u * 16) = o;
    }
}

// ---------------- f16 -> int8 (16-half units; strided-capable), packed ----------------
__device__ __forceinline__ unsigned pk4h(unsigned h2a, unsigned h2b, float s) {
    __half2 a = *(__half2*)&h2a, b = *(__half2*)&h2b;
    return pk4(__low2float(a), __high2float(a), __low2float(b), __high2float(b), s);
}
__global__ void k_quanth(const __half* __restrict__ x, int8_t* __restrict__ q, long nu,
                         int rshift, long cmask, long ld,
                         const unsigned* __restrict__ slots, int slot) {
    float s = slot_scale(slots, slot);
    long gs = (long)gridDim.x * blockDim.x;
    for (long u = blockIdx.x * (long)blockDim.x + threadIdx.x; u < nu; u += gs) {
        long row = u >> rshift;
        long cu = u & cmask;
        const int4* src = (const int4*)(x + row * ld + cu * 16);
        int4 a = src[0], b = src[1];
        int4 o;
        o.x = (int)pk4h((unsigned)a.x, (unsigned)a.y, s);
        o.y = (int)pk4h((unsigned)a.z, (unsigned)a.w, s);
        o.z = (int)pk4h((unsigned)b.x, (unsigned)b.y, s);
        o.w = (int)pk4h((unsigned)b.z, (unsigned)b.w, s);
        *(int4*)(q + u * 16) = o;
    }
}

// ---------------- rope cos/sin table ----------------
__global__ void k_ropetab(const int* __restrict__ pos, float* __restrict__ ct,
                          float* __restrict__ st) {
    int tid = blockIdx.x * blockDim.x + threadIdx.x;
    if (tid >= SEQ * 64) return;
    int i = tid & 63, s = tid >> 6;
    double inv = 1.0 / pow(10000.0, (double)((float)(2 * i) * (1.0f / 128.0f)));
    float invf = (float)inv;
    float angf = (float)pos[s] * invf;
    double a = (double)angf;
    ct[tid] = (float)cos(a);
    st[tid] = (float)sin(a);
}

// ---------------- transpose + quantize (V f16 -> V^T int8) ----------------
__global__ void k_transq(const __half* __restrict__ src, long lds_, int8_t* __restrict__ dst,
                         long ldd, const unsigned* __restrict__ slots, int slot) {
    __shared__ float t[32][33];
    float s = slot_scale(slots, slot);
    int bx = blockIdx.x, by = blockIdx.y;
    int tid = threadIdx.x;
    int c = tid & 31, r0 = tid >> 5;
    #pragma unroll
    for (int j = 0; j < 4; j++) {
        int r = r0 + j * 8;
        t[r][c] = __half2float(src[(long)(by * 32 + r) * lds_ + bx * 32 + c]);
    }
    __syncthreads();
    int d = tid >> 3, k4 = (tid & 7) * 4;
    unsigned pa = 0;
    #pragma unroll
    for (int j = 0; j < 4; j++) {
        int iv = q8v(t[k4 + j][d], s);
        pa |= ((unsigned)(uint8_t)(int8_t)iv) << (8 * j);
    }
    *(unsigned*)(dst + (long)(bx * 32 + d) * ldd + by * 32 + k4) = pa;
}

// ---------------- int8 GEMM 128x128, BK=128 (proven), + RoPE/absmax epilogues -----------
// ropemode: 0 = plain f32 store; 1 = rope all cols (Q, f16 out), partial->pQ[blockIdx];
//           2 = KV f16 out: bn<8 rope (K)->pK, bn>=8 absmax (V)->pV
__global__ __launch_bounds__(256) void k_gemm_i8(
    const int8_t* __restrict__ A, const int8_t* __restrict__ B, void* __restrict__ Cv,
    int N, int K, unsigned* slots,
    int slotA, int slotB, int slotB2, int nsplit,
    float* pQ, float* pK, float* pV, int ropemode,
    const float* __restrict__ ct, const float* __restrict__ st) {
    __shared__ int8_t POOL[65536];
    int8_t (*As)[16384] = (int8_t(*)[16384])POOL;
    int8_t (*Bs)[16384] = (int8_t(*)[16384])(POOL + 32768);
    float* Cf = (float*)Cv;
    __half* Ch = (__half*)Cv;
    const v4i vzero = {0, 0, 0, 0};
    int tid = threadIdx.x, lane = tid & 63, wid = tid >> 6;
    int nbx = N >> 7;
    int nwg = gridDim.x, wg = blockIdx.x;
    int cpx = nwg >> 3;
    int swz = (wg & 7) * cpx + (wg >> 3);
    int bm = swz / nbx, bn = swz % nbx;
    long rowA0 = (long)bm * 128, colB0 = (long)bn * 128;
    int wrow = (wid >> 1) * 64, wcol = (wid & 1) * 64;
    int lr = lane >> 3;
    int swc = ((lane & 7) ^ lr) * 16;
    const int8_t* ga = A + (rowA0 + wid * 8 + lr) * (long)K + swc;
    const int8_t* gb = B + (colB0 + wid * 8 + lr) * (long)K + swc;
    v4i acc[4][4];
    #pragma unroll
    for (int m = 0; m < 4; m++)
        #pragma unroll
        for (int n = 0; n < 4; n++) acc[m][n] = vzero;

    auto STAGE = [&](int buf, int kt) {
        #pragma unroll
        for (int i = 0; i < 4; i++) {
            gload16(ga + kt + (long)(i * 32) * K, &As[buf][(wid * 8 + i * 32) * 128]);
            gload16(gb + kt + (long)(i * 32) * K, &Bs[buf][(wid * 8 + i * 32) * 128]);
        }
    };
    auto COMPUTE = [&](int buf) {
        #pragma unroll
        for (int ks = 0; ks < 2; ks++) {
            v4i af[4], bf[4];
            #pragma unroll
            for (int m = 0; m < 4; m++) {
                int row = wrow + m * 16 + (lane & 15);
                af[m] = *(const v4i*)(&As[buf][row * 128 + (((ks * 4 + (lane >> 4)) ^ (row & 7)) * 16)]);
            }
            #pragma unroll
            for (int n = 0; n < 4; n++) {
                int row = wcol + n * 16 + (lane & 15);
                bf[n] = *(const v4i*)(&Bs[buf][row * 128 + (((ks * 4 + (lane >> 4)) ^ (row & 7)) * 16)]);
            }
            #pragma unroll
            for (int m = 0; m < 4; m++)
                #pragma unroll
                for (int n = 0; n < 4; n++)
                    acc[m][n] = __builtin_amdgcn_mfma_i32_16x16x64_i8(af[m], bf[n], acc[m][n], 0, 0, 0);
        }
    };

    STAGE(0, 0);
    VMCNT0;
    __syncthreads();
    int nt = K >> 7, cur = 0;
    for (int t = 0; t < nt - 1; t++) {
        STAGE(cur ^ 1, (t + 1) << 7);
        COMPUTE(cur);
        VMCNT0;
        __syncthreads();
        cur ^= 1;
    }
    COMPUTE(cur);

    float sA = slot_scale(slots, slotA);
    float sB1s = slot_scale(slots, slotB);
    float sB2s = slot_scale(slots, slotB2);
    int qc = lane & 15, rgrp = (lane >> 4) << 2;
    if (ropemode == 1 || (ropemode == 2 && bn < 8)) {
        __syncthreads();                      // As/Bs dead for all waves
        float* EX = (float*)POOL;             // 128x128 f32, XOR-swizzled
        #pragma unroll
        for (int m = 0; m < 4; m++)
            #pragma unroll
            for (int n = 0; n < 4; n++) {
                int coll = wcol + n * 16 + qc;
                #pragma unroll
                for (int r = 0; r < 4; r++) {
                    int rowl = wrow + m * 16 + rgrp + r;
                    EX[rowl * 128 + (coll ^ ((rowl & 1) << 4))] = sA * sB1s * (float)acc[m][n][r];
                }
            }
        __syncthreads();
        float am = 0.f;
        #pragma unroll
        for (int m = 0; m < 4; m++)
            #pragma unroll
            for (int n = 0; n < 4; n++) {
                int coll = wcol + n * 16 + qc;
                #pragma unroll
                for (int r = 0; r < 4; r++) {
                    int rowl = wrow + m * 16 + rgrp + r;
                    long srow = rowA0 + rowl;
                    float self = EX[rowl * 128 + (coll ^ ((rowl & 1) << 4))];
                    float pv = EX[rowl * 128 + ((coll ^ 64) ^ ((rowl & 1) << 4))];
                    float c = ct[srow * 64 + (coll & 63)];
                    float sn = st[srow * 64 + (coll & 63)];
                    float o = (coll < 64) ? self * c - pv * sn : self * c + pv * sn;
                    am = fmaxf(am, fabsf(o));
                    Ch[srow * N + colB0 + coll] = __float2half(o);
                }
            }
        block_amax_part(am, (ropemode == 1) ? pQ + blockIdx.x : pK + bm * 8 + (bn & 7));
    } else if (ropemode == 2) {               // V tile: scale + f16 store + absmax
        float am = 0.f;
        #pragma unroll
        for (int m = 0; m < 4; m++) {
            long row0 = rowA0 + wrow + m * 16 + rgrp;
            #pragma unroll
            for (int n = 0; n < 4; n++) {
                int col = (int)colB0 + wcol + n * 16 + qc;
                float sc = sA * ((col < nsplit) ? sB1s : sB2s);
                __half* cp = Ch + row0 * N + col;
                #pragma unroll
                for (int r = 0; r < 4; r++) {
                    float val = sc * (float)acc[m][n][r];
                    cp[(long)r * N] = __float2half(val);
                    am = fmaxf(am, fabsf(val));
                }
            }
        }
        block_amax_part(am, pV + bm * 8 + (bn & 7));
    } else {
        #pragma unroll
        for (int m = 0; m < 4; m++) {
            long row0 = rowA0 + wrow + m * 16 + rgrp;
            #pragma unroll
            for (int n = 0; n < 4; n++) {
                int col = (int)colB0 + wcol + n * 16 + qc;
                float sc = sA * ((col < nsplit) ? sB1s : sB2s);
                float* cp = Cf + row0 * N + col;
                #pragma unroll
                for (int r = 0; r < 4; r++) cp[(long)r * N] = sc * (float)acc[m][n][r];
            }
        }
    }
}

// ---------------- two-pass flash attention (fused-exp softmax, 37.9KB LDS) --------------
__global__ __launch_bounds__(256) void k_attn(
    const int8_t* __restrict__ Qq, const int8_t* __restrict__ Kq, const int8_t* __restrict__ Vtq,
    __half* __restrict__ AO, unsigned* slots) {
    __shared__ int8_t Ks[2][64 * 128];
    __shared__ int8_t Vs[2][128 * 64];   // paired-row swizzled; [0] doubles as Q staging
    __shared__ unsigned Ps[4 * 320];     // packed-P (20-dword stride per warp)
    __shared__ int smx[4];
    const v4i vzero = {0, 0, 0, 0};
    const int NEGS = -(1 << 29);
    const float MAGIC = 12582912.0f;  // 1.5*2^23, RNE rounding
    int tid = threadIdx.x, lane = tid & 63, w = tid >> 6;
    int qlan = lane & 15, g = lane >> 4;
    int idx = blockIdx.x;
    int qb = 31 - (idx >> 5), h = idx & 31, kvh = h >> 2;   // long blocks first
    float sq = slot_scale(slots, 5), sk = slot_scale(slots, 6);
    float spv = slot_scale(slots, 7) * (1.0f / 127.0f);
    float c2 = sq * sk * 0.08838834764831845f * 1.4426950408889634f;
    int lr8 = lane >> 3;
    int swc = ((lane & 7) ^ lr8) * 16;
    const int8_t* kbase = Kq + ((long)(w * 8 + lr8)) * KVDIM + kvh * 128 + swc;
    // V staging: per-thread paired-row inverse source (chunks tid, tid+256)
    int vr0_, vc0_, vr1_, vc1_;
    prsw_inv(tid, vr0_, vc0_);
    prsw_inv(tid + 256, vr1_, vc1_);
    const int8_t* sV0 = Vtq + ((long)kvh * 128 + vr0_) * SEQ + vc0_ * 16;
    const int8_t* sV1 = Vtq + ((long)kvh * 128 + vr1_) * SEQ + vc1_ * 16;
    auto STAGE_K = [&](int buf, int kt) {
        #pragma unroll
        for (int i = 0; i < 2; i++)
            gload16(kbase + ((long)kt * 64 + i * 32) * KVDIM, &Ks[buf][(w * 8 + i * 32) * 128]);
    };
    auto STAGE_V = [&](int buf, int kt) {
        gload16(sV0 + kt * 64, &Vs[buf][w * 1024]);
        gload16(sV1 + kt * 64, &Vs[buf][w * 1024 + 4096]);
    };
    // stage Q (64x128, row&7 XOR layout) into Vs space (dead until pass 2)
    {
        int8_t* Qstage = &Vs[0][0];
        const int8_t* qbase = Qq + ((long)qb * 64 + w * 8 + lr8) * HID + h * 128 + swc;
        #pragma unroll
        for (int i = 0; i < 2; i++)
            gload16(qbase + (long)(i * 32) * HID, &Qstage[(w * 8 + i * 32) * 128]);
    }
    STAGE_K(0, 0);
    VMCNT0;
    __syncthreads();
    v4i aq[2];
    #pragma unroll
    for (int ks = 0; ks < 2; ks++) {
        int row = w * 16 + qlan;
        aq[ks] = *(const v4i*)(&Vs[0][row * 128 + (((ks * 4 + g) ^ (row & 7)) * 16)]);
    }
    __syncthreads();   // all aq reads done before Vs reuse
    int mi = -(1 << 30);
    float l = 0.f;
    int buf = 0;
    // ---- pass 1: int row-max + fused-exp denominator ----
    for (int kt = 0; kt <= qb; kt++) {
        if (kt < qb) STAGE_K(buf ^ 1, kt + 1);
        v4i sf[4] = {vzero, vzero, vzero, vzero};
        __builtin_amdgcn_s_setprio(1);
        #pragma unroll
        for (int ks = 0; ks < 2; ks++)
            #pragma unroll
            for (int f = 0; f < 4; f++) {
                int row = f * 16 + qlan;
                v4i bk = *(const v4i*)(&Ks[buf][row * 128 + (((ks * 4 + g) ^ (row & 7)) * 16)]);
                sf[f] = __builtin_amdgcn_mfma_i32_16x16x64_i8(bk, aq[ks], sf[f], 0, 0, 0);
            }
        __builtin_amdgcn_s_setprio(0);
        int sv[16];
        if (kt == qb) {
            int qthr = w * 16 + qlan;
            #pragma unroll
            for (int f = 0; f < 4; f++)
                #pragma unroll
                for (int r = 0; r < 4; r++) {
                    int kl = f * 16 + g * 4 + r;
                    sv[f * 4 + r] = (kl > qthr) ? NEGS : sf[f][r];
                }
        } else {
            #pragma unroll
            for (int f = 0; f < 4; f++)
                #pragma unroll
                for (int r = 0; r < 4; r++) sv[f * 4 + r] = sf[f][r];
        }
        int tm = sv[0];
        #pragma unroll
        for (int e = 1; e < 16; e++) tm = tm > sv[e] ? tm : sv[e];
        tm = max(tm, __shfl_xor(tm, 16, 64));
        tm = max(tm, __shfl_xor(tm, 32, 64));
        int mn = tm > mi ? tm : mi;
        float nb = -c2 * (float)mn;
        float esc = fexp2(fmaf((float)mi, c2, nb));
        float es = 0.f;
        #pragma unroll
        for (int e = 0; e < 16; e++) es += fexp2(fmaf((float)sv[e], c2, nb));
        es += __shfl_xor(es, 16, 64);
        es += __shfl_xor(es, 32, 64);
        l = l * esc + es;
        mi = mn;
        VMCNT0;
        __syncthreads();
        buf ^= 1;
    }
    // fused quant bias: p_q127 = exp2(c2*s - Bq), Bq = c2*m + log2(l) - log2(127)
    float Bq = fmaf(c2, (float)mi, __log2f(l) - 6.9886846867721655f);
    // ---- pass 2 ----
    int pwr = w * 320;
    v4i of[8];
    #pragma unroll
    for (int nf = 0; nf < 8; nf++) of[nf] = vzero;
    STAGE_K(0, 0);
    STAGE_V(0, 0);
    VMCNT0;
    __syncthreads();
    buf = 0;
    for (int kt = 0; kt <= qb; kt++) {
        if (kt < qb) { STAGE_K(buf ^ 1, kt + 1); STAGE_V(buf ^ 1, kt + 1); }
        v4i sf[4] = {vzero, vzero, vzero, vzero};
        __builtin_amdgcn_s_setprio(1);
        #pragma unroll
        for (int ks = 0; ks < 2; ks++)
            #pragma unroll
            for (int f = 0; f < 4; f++) {
                int row = f * 16 + qlan;
                v4i bk = *(const v4i*)(&Ks[buf][row * 128 + (((ks * 4 + g) ^ (row & 7)) * 16)]);
                sf[f] = __builtin_amdgcn_mfma_i32_16x16x64_i8(bk, aq[ks], sf[f], 0, 0, 0);
            }
        __builtin_amdgcn_s_setprio(0);
        if (kt == qb) {
            int qthr = w * 16 + qlan;
            #pragma unroll
            for (int f = 0; f < 4; f++) {
                unsigned pk = 0;
                #pragma unroll
                for (int r = 0; r < 4; r++) {
                    int kl = f * 16 + g * 4 + r;
                    int s = (kl > qthr) ? NEGS : sf[f][r];
                    float t = fexp2(fmaf((float)s, c2, -Bq));
                    unsigned u = __float_as_uint(t + MAGIC) & 127u;
                    pk |= u << (8 * r);
                }
                Ps[pwr + (4 * f + g) * 20 + qlan] = pk;
            }
        } else {
            #pragma unroll
            for (int f = 0; f < 4; f++) {
                unsigned pk = 0;
                #pragma unroll
                for (int r = 0; r < 4; r++) {
                    float t = fexp2(fmaf((float)sf[f][r], c2, -Bq));
                    unsigned u = __float_as_uint(t + MAGIC) & 127u;
                    pk |= u << (8 * r);
                }
                Ps[pwr + (4 * f + g) * 20 + qlan] = pk;
            }
        }
        int rb = pwr + 80 * g + qlan;
        v4i ap;
        ap[0] = (int)Ps[rb];
        ap[1] = (int)Ps[rb + 20];
        ap[2] = (int)Ps[rb + 40];
        ap[3] = (int)Ps[rb + 60];
        __builtin_amdgcn_s_setprio(1);
        #pragma unroll
        for (int nf = 0; nf < 8; nf++) {
            int row = nf * 16 + qlan;
            v4i bv = *(const v4i*)(&Vs[buf][prsw(row, g) * 16]);
            of[nf] = __builtin_amdgcn_mfma_i32_16x16x64_i8(ap, bv, of[nf], 0, 0, 0);
        }
        __builtin_amdgcn_s_setprio(0);
        VMCNT0;
        __syncthreads();
        buf ^= 1;
    }
    int mymax = 0;
    #pragma unroll
    for (int nf = 0; nf < 8; nf++)
        #pragma unroll
        for (int r = 0; r < 4; r++) {
            int val = of[nf][r];
            int av = val < 0 ? -val : val;
            mymax = av > mymax ? av : mymax;
            int qg = qb * 64 + w * 16 + 4 * g + r;
            AO[(long)qg * HID + h * 128 + nf * 16 + qlan] = __float2half(spv * (float)val);
        }
    #pragma unroll
    for (int off = 1; off < 64; off <<= 1) {
        int o2 = __shfl_xor(mymax, off, 64);
        mymax = o2 > mymax ? o2 : mymax;
    }
    if (lane == 0) smx[w] = mymax;
    __syncthreads();
    if (tid == 0) {
        int mm = max(max(smx[0], smx[1]), max(smx[2], smx[3]));
        atomicMax(slots + (8 << 5), (unsigned)mm);   // staggered retirement
    }
}

// ---------------- quantize attn_out (f16 -> int8), packed ----------------
__global__ void k_quant_ao(const __half* __restrict__ a, int8_t* __restrict__ q,
                           unsigned* slots) {
    float sv = slot_scale(slots, 7);
    float spv = (1.0f / 127.0f) * sv;
    float amax = spv * (float)(int)slots[8 << 5];
    float s = fmaxf(amax / 127.0f, 1e-8f);
    long nu = (long)SEQ * HID / 16;
    long gs = (long)gridDim.x * blockDim.x;
    for (long u = blockIdx.x * (long)blockDim.x + threadIdx.x; u < nu; u += gs) {
        const int4* src = (const int4*)(a + u * 16);
        int4 x = src[0], y = src[1];
        int4 o;
        o.x = (int)pk4h((unsigned)x.x, (unsigned)x.y, s);
        o.y = (int)pk4h((unsigned)x.z, (unsigned)x.w, s);
        o.z = (int)pk4h((unsigned)y.x, (unsigned)y.y, s);
        o.w = (int)pk4h((unsigned)y.z, (unsigned)y.w, s);
        *(int4*)(q + u * 16) = o;
    }
    if (blockIdx.x == 0 && threadIdx.x == 0) slots[9 << 5] = __float_as_uint(amax);
}

extern "C" void kernel_launch(void* const* d_in, const int* in_sizes, int n_in,
                              void* d_out, int out_size, void* d_ws, size_t ws_size,
                              hipStream_t stream) {
    (void)in_sizes; (void)n_in; (void)out_size;
    const float* hid = (const float*)d_in[0];
    const int* pos = (const int*)d_in[2];
    const float* wqp = (const float*)d_in[3];
    const float* wkp = (const float*)d_in[4];
    const float* wvp = (const float*)d_in[5];
    const float* wop = (const float*)d_in[6];
    float* out = (float*)d_out;
    char* ws = (char*)d_ws;

    size_t o = 0;
    auto alloc = [&](size_t sz) { size_t r = o; o += (sz + 255) & ~(size_t)255; return r; };
    unsigned* slots = (unsigned*)(ws + alloc(2048));
    float* P0 = (float*)(ws + alloc(2048 * 4));      // absmax5 partials
    float* P1 = (float*)(ws + alloc(512 * 4));       // gemm1 Q-rope partials
    float* P2 = (float*)(ws + alloc(128 * 4));       // gemm2 K-rope partials
    float* P3 = (float*)(ws + alloc(128 * 4));       // gemm2 V partials
    int8_t* Xq   = (int8_t*)(ws + alloc((size_t)SEQ * HID));      // later reused as AOq
    int8_t* Wqq  = (int8_t*)(ws + alloc((size_t)HID * HID));
    int8_t* Woq  = (int8_t*)(ws + alloc((size_t)HID * HID));
    int8_t* Wkvq = (int8_t*)(ws + alloc((size_t)KVCAT * HID));
    __half* Qf   = (__half*)(ws + alloc((size_t)SEQ * HID * 2));  // later reused as AOh
    __half* KVf  = (__half*)(ws + alloc((size_t)SEQ * KVCAT * 2));
    int8_t* Qq   = (int8_t*)(ws + alloc((size_t)SEQ * HID));
    int8_t* Kq   = (int8_t*)(ws + alloc((size_t)SEQ * KVDIM));
    int8_t* Vtq  = (int8_t*)(ws + alloc((size_t)KVDIM * SEQ));
    float*  ctab = (float*)(ws + alloc((size_t)SEQ * 64 * 4));
    float*  stab = (float*)(ws + alloc((size_t)SEQ * 64 * 4));
    if (ws_size < o) return;
    __half* AOh = Qf;
    int8_t* AOq = Xq;

    (void)hipMemsetAsync(slots, 0, 2048, stream);
    k_ropetab<<<SEQ * 64 / 256, 256, 0, stream>>>(pos, ctab, stab);
    k_absmax5<<<2048, 256, 0, stream>>>(hid, wqp, wkp, wvp, wop, P0);
    k_reduceA<<<1, 256, 0, stream>>>(P0, slots);
    k_quant5<<<2560, 256, 0, stream>>>(hid, wqp, wkp, wvp, wop,
                                       Xq, Wqq, Wkvq, Wkvq + (size_t)KVDIM * HID, Woq, slots);
    k_gemm_i8<<<512, 256, 0, stream>>>(Xq, Wqq, Qf, HID, HID, slots,
                                       0, 1, 1, 1 << 30, P1, nullptr, nullptr, 1, ctab, stab);
    k_gemm_i8<<<256, 256, 0, stream>>>(Xq, Wkvq, KVf, KVCAT, HID, slots,
                                       0, 2, 3, KVDIM, nullptr, P2, P3, 2, ctab, stab);
    k_reduceB<<<1, 256, 0, stream>>>(P1, P2, P3, slots);
    const long CALL = 0x3FFFFFFFL;
    k_quanth<<<1024, 256, 0, stream>>>(Qf, Qq, (long)SEQ * HID / 16, 40, CALL, 0, slots, 5);
    k_quanth<<<512, 256, 0, stream>>>(KVf, Kq, (long)SEQ * KVDIM / 16, 6, 63, KVCAT, slots, 6);
    k_transq<<<dim3(32, 64), 256, 0, stream>>>(KVf + KVDIM, KVCAT, Vtq, SEQ, slots, 7);
    k_attn<<<1024, 256, 0, stream>>>(Qq, Kq, Vtq, AOh, slots);
    k_quant_ao<<<1024, 256, 0, stream>>>(AOh, AOq, slots);
    k_gemm_i8<<<512, 256, 0, stream>>>(AOq, Woq, out, HID, HID, slots,
                                       9, 4, 4, 1 << 30, nullptr, nullptr, nullptr, 0,
                                       nullptr, nullptr);
}

// Round 16
// 286.490 us; speedup vs baseline: 1.0819x; 1.0124x over previous
//
#include <hip/hip_runtime.h>
#include <hip/hip_fp16.h>
#include <stdint.h>

#define SEQ   2048
#define HID   4096
#define NH    32
#define NKV   8
#define KVDIM 1024   // NKV*HD
#define KVCAT 2048   // KVDIM*2

typedef int v4i __attribute__((ext_vector_type(4)));

#define VMCNT0 asm volatile("s_waitcnt vmcnt(0)" ::: "memory")

// async global->LDS 16B: per-lane global source, wave-uniform LDS base (+lane*16 by HW)
__device__ __forceinline__ void gload16(const void* g, void* l) {
    __builtin_amdgcn_global_load_lds(
        (const __attribute__((address_space(1))) void*)(uintptr_t)g,
        (__attribute__((address_space(3))) void*)(uintptr_t)l, 16, 0, 0);
}

// paired-row swizzle: 16B-chunk index for (row, c) in a [R][64] int8 tile
__device__ __forceinline__ int prsw(int row, int c) {
    return (row >> 1) * 8 + (row & 1) * 4 + (c ^ ((row >> 1) & 3));
}
// inverse: dest chunk d -> (row, c)
__device__ __forceinline__ void prsw_inv(int d, int& row, int& c) {
    int rp = d >> 3, rem = d & 7;
    row = 2 * rp + (rem >> 2);
    c = (rem & 3) ^ (rp & 3);
}

__device__ __forceinline__ float slot_scale(const unsigned* slots, int slot) {
    return fmaxf(__uint_as_float(slots[slot << 5]) / 127.0f, 1e-8f);
}

__device__ __forceinline__ int q8v(float x, float s) {
    int v = (int)rintf(x / s);
    return v < -127 ? -127 : (v > 127 ? 127 : v);
}

__device__ __forceinline__ unsigned pk4(float a, float b, float c, float d, float s) {
    return (unsigned)(uint8_t)(int8_t)q8v(a, s)
         | ((unsigned)(uint8_t)(int8_t)q8v(b, s) << 8)
         | ((unsigned)(uint8_t)(int8_t)q8v(c, s) << 16)
         | ((unsigned)(uint8_t)(int8_t)q8v(d, s) << 24);
}

__device__ __forceinline__ float fexp2(float x) {
    float r; asm("v_exp_f32 %0, %1" : "=v"(r) : "v"(x)); return r;
}

__device__ __forceinline__ float fmax4a(float4 x) {
    return fmaxf(fmaxf(fabsf(x.x), fabsf(x.y)), fmaxf(fabsf(x.z), fabsf(x.w)));
}

// block-level reduce (4 waves), ONE plain store (no atomic contention)
__device__ __forceinline__ void block_amax_part(float m, float* dst) {
    __shared__ float sm[4];
    int lane = threadIdx.x & 63, w = threadIdx.x >> 6;
    for (int off = 32; off; off >>= 1) m = fmaxf(m, __shfl_xor(m, off, 64));
    if (lane == 0) sm[w] = m;
    __syncthreads();
    if (threadIdx.x == 0)
        *dst = fmaxf(fmaxf(sm[0], sm[1]), fmaxf(sm[2], sm[3]));
    __syncthreads();
}

// ---------------- fused absmax: blocks partitioned per tensor ----------------
#define NV0 ((long)SEQ * HID / 4)     // 2M vecs
#define NV1 ((long)HID * HID / 4)     // 4M vecs
#define NV2 ((long)KVDIM * HID / 4)   // 1M vecs
__global__ void k_absmax5(const float* __restrict__ a0, const float* __restrict__ a1,
                          const float* __restrict__ a2, const float* __restrict__ a3,
                          const float* __restrict__ a4, float* __restrict__ part) {
    int b = blockIdx.x;
    const float* p; long n; int lb, nb;
    if (b < 342)       { p = a0; n = NV0; lb = b;        nb = 342; }
    else if (b < 1025) { p = a1; n = NV1; lb = b - 342;  nb = 683; }
    else if (b < 1196) { p = a2; n = NV2; lb = b - 1025; nb = 171; }
    else if (b < 1367) { p = a3; n = NV2; lb = b - 1196; nb = 171; }
    else               { p = a4; n = NV1; lb = b - 1367; nb = 681; }
    long str = (long)nb * 256;
    float mm[8] = {0.f, 0.f, 0.f, 0.f, 0.f, 0.f, 0.f, 0.f};
    long v = (long)lb * 256 + threadIdx.x;
    for (; v + 7 * str < n; v += 8 * str) {
        float4 t[8];
        #pragma unroll
        for (int j = 0; j < 8; j++) t[j] = *(const float4*)(p + (v + j * str) * 4);
        #pragma unroll
        for (int j = 0; j < 8; j++) mm[j] = fmaxf(mm[j], fmax4a(t[j]));
    }
    for (; v < n; v += str) mm[0] = fmaxf(mm[0], fmax4a(*(const float4*)(p + v * 4)));
    float m = fmaxf(fmaxf(fmaxf(mm[0], mm[1]), fmaxf(mm[2], mm[3])),
                    fmaxf(fmaxf(mm[4], mm[5]), fmaxf(mm[6], mm[7])));
    block_amax_part(m, part + blockIdx.x);
}

// ---------------- reduce partials -> slots 0..4 ----------------
__global__ void k_reduceA(const float* __restrict__ part, unsigned* slots) {
    __shared__ float sm[4];
    const int lo[5] = {0, 342, 1025, 1196, 1367};
    const int hi[5] = {342, 1025, 1196, 1367, 2048};
    int t = threadIdx.x, lane = t & 63, w = t >> 6;
    for (int s = 0; s < 5; s++) {
        float m = 0.f;
        for (int i = lo[s] + t; i < hi[s]; i += 256) m = fmaxf(m, part[i]);
        for (int off = 32; off; off >>= 1) m = fmaxf(m, __shfl_xor(m, off, 64));
        if (lane == 0) sm[w] = m;
        __syncthreads();
        if (t == 0)
            slots[s << 5] = __float_as_uint(fmaxf(fmaxf(sm[0], sm[1]), fmaxf(sm[2], sm[3])));
        __syncthreads();
    }
}

// ---------------- reduce partials -> slots 5 (q), 6 (k), 7 (v) ----------------
__global__ void k_reduceB(const float* __restrict__ p1, const float* __restrict__ p2,
                          const float* __restrict__ p3, unsigned* slots) {
    __shared__ float sm[4];
    int t = threadIdx.x, lane = t & 63, w = t >> 6;
    const float* ps[3] = {p1, p2, p3};
    const int cnt[3] = {512, 128, 128};
    const int sl[3] = {5, 6, 7};
    for (int s = 0; s < 3; s++) {
        float m = 0.f;
        for (int i = t; i < cnt[s]; i += 256) m = fmaxf(m, ps[s][i]);
        for (int off = 32; off; off >>= 1) m = fmaxf(m, __shfl_xor(m, off, 64));
        if (lane == 0) sm[w] = m;
        __syncthreads();
        if (t == 0)
            slots[sl[s] << 5] = __float_as_uint(fmaxf(fmaxf(sm[0], sm[1]), fmaxf(sm[2], sm[3])));
        __syncthreads();
    }
}

// ---------------- fused quantize of hid, wq, wk, wv, wo (balanced partitions) ----------
#define NU0 ((long)SEQ * HID / 16)
#define NU1 ((long)HID * HID / 16)
#define NU2 ((long)KVDIM * HID / 16)
__global__ void k_quant5(const float* __restrict__ a0, const float* __restrict__ a1,
                         const float* __restrict__ a2, const float* __restrict__ a3,
                         const float* __restrict__ a4,
                         int8_t* __restrict__ d0, int8_t* __restrict__ d1,
                         int8_t* __restrict__ d2, int8_t* __restrict__ d3,
                         int8_t* __restrict__ d4,
                         const unsigned* __restrict__ slots) {
    int b = blockIdx.x;
    const float* p; int8_t* d; long n; int slot, lb, nb;
    if (b < 512)       { p = a0; d = d0; n = NU0; slot = 0; lb = b;        nb = 512; }
    else if (b < 1536) { p = a1; d = d1; n = NU1; slot = 1; lb = b - 512;  nb = 1024; }
    else if (b < 1792) { p = a2; d = d2; n = NU2; slot = 2; lb = b - 1536; nb = 256; }
    else if (b < 2048) { p = a3; d = d3; n = NU2; slot = 3; lb = b - 1792; nb = 256; }
    else               { p = a4; d = d4; n = NU1; slot = 4; lb = b - 2048; nb = 1024; }
    float s = slot_scale(slots, slot);
    long str = (long)nb * 256;
    for (long u = (long)lb * 256 + threadIdx.x; u < n; u += str) {
        const float4* src = (const float4*)(p + u * 16);
        float4 t0 = src[0], t1 = src[1], t2 = src[2], t3 = src[3];
        int4 o;
        o.x = (int)pk4(t0.x, t0.y, t0.z, t0.w, s);
        o.y = (int)pk4(t1.x, t1.y, t1.z, t1.w, s);
        o.z = (int)pk4(t2.x, t2.y, t2.z, t2.w, s);
        o.w = (int)pk4(t3.x, t3.y, t3.z, t3.w, s);
        *(int4*)(d + u * 16) = o;
    }
}

// ---------------- f16 -> int8 (16-half units; strided-capable), packed ----------------
__device__ __forceinline__ unsigned pk4h(unsigned h2a, unsigned h2b, float s) {
    __half2 a = *(__half2*)&h2a, b = *(__half2*)&h2b;
    return pk4(__low2float(a), __high2float(a), __low2float(b), __high2float(b), s);
}
__global__ void k_quanth(const __half* __restrict__ x, int8_t* __restrict__ q, long nu,
                         int rshift, long cmask, long ld,
                         const unsigned* __restrict__ slots, int slot) {
    float s = slot_scale(slots, slot);
    long gs = (long)gridDim.x * blockDim.x;
    for (long u = blockIdx.x * (long)blockDim.x + threadIdx.x; u < nu; u += gs) {
        long row = u >> rshift;
        long cu = u & cmask;
        const int4* src = (const int4*)(x + row * ld + cu * 16);
        int4 a = src[0], b = src[1];
        int4 o;
        o.x = (int)pk4h((unsigned)a.x, (unsigned)a.y, s);
        o.y = (int)pk4h((unsigned)a.z, (unsigned)a.w, s);
        o.z = (int)pk4h((unsigned)b.x, (unsigned)b.y, s);
        o.w = (int)pk4h((unsigned)b.z, (unsigned)b.w, s);
        *(int4*)(q + u * 16) = o;
    }
}

// ---------------- rope cos/sin table ----------------
__global__ void k_ropetab(const int* __restrict__ pos, float* __restrict__ ct,
                          float* __restrict__ st) {
    int tid = blockIdx.x * blockDim.x + threadIdx.x;
    if (tid >= SEQ * 64) return;
    int i = tid & 63, s = tid >> 6;
    double inv = 1.0 / pow(10000.0, (double)((float)(2 * i) * (1.0f / 128.0f)));
    float invf = (float)inv;
    float angf = (float)pos[s] * invf;
    double a = (double)angf;
    ct[tid] = (float)cos(a);
    st[tid] = (float)sin(a);
}

// ---------------- transpose + quantize (V f16 -> V^T int8) ----------------
__global__ void k_transq(const __half* __restrict__ src, long lds_, int8_t* __restrict__ dst,
                         long ldd, const unsigned* __restrict__ slots, int slot) {
    __shared__ float t[32][33];
    float s = slot_scale(slots, slot);
    int bx = blockIdx.x, by = blockIdx.y;
    int tid = threadIdx.x;
    int c = tid & 31, r0 = tid >> 5;
    #pragma unroll
    for (int j = 0; j < 4; j++) {
        int r = r0 + j * 8;
        t[r][c] = __half2float(src[(long)(by * 32 + r) * lds_ + bx * 32 + c]);
    }
    __syncthreads();
    int d = tid >> 3, k4 = (tid & 7) * 4;
    unsigned pa = 0;
    #pragma unroll
    for (int j = 0; j < 4; j++) {
        int iv = q8v(t[k4 + j][d], s);
        pa |= ((unsigned)(uint8_t)(int8_t)iv) << (8 * j);
    }
    *(unsigned*)(dst + (long)(bx * 32 + d) * ldd + by * 32 + k4) = pa;
}

// ---------------- int8 GEMM 128x128, BK=128, + RoPE/absmax epilogues -------------------
// ropemode: 0 = plain f32 store; 1 = rope all cols (Q, f16 out), partial->pQ[blockIdx];
//           2 = KV f16 out: bn<8 rope (K)->pK, bn>=8 absmax (V)->pV
__global__ __launch_bounds__(256) void k_gemm_i8(
    const int8_t* __restrict__ A, const int8_t* __restrict__ B, void* __restrict__ Cv,
    int N, int K, unsigned* slots,
    int slotA, int slotB, int slotB2, int nsplit,
    float* pQ, float* pK, float* pV, int ropemode,
    const float* __restrict__ ct, const float* __restrict__ st) {
    __shared__ int8_t POOL[65536];
    int8_t (*As)[16384] = (int8_t(*)[16384])POOL;
    int8_t (*Bs)[16384] = (int8_t(*)[16384])(POOL + 32768);
    float* Cf = (float*)Cv;
    __half* Ch = (__half*)Cv;
    const v4i vzero = {0, 0, 0, 0};
    int tid = threadIdx.x, lane = tid & 63, wid = tid >> 6;
    int nbx = N >> 7;
    int nwg = gridDim.x, wg = blockIdx.x;
    int cpx = nwg >> 3;
    int swz = (wg & 7) * cpx + (wg >> 3);
    int bm = swz / nbx, bn = swz % nbx;
    long rowA0 = (long)bm * 128, colB0 = (long)bn * 128;
    int wrow = (wid >> 1) * 64, wcol = (wid & 1) * 64;
    int lr = lane >> 3;
    int swc = ((lane & 7) ^ lr) * 16;
    const int8_t* ga = A + (rowA0 + wid * 8 + lr) * (long)K + swc;
    const int8_t* gb = B + (colB0 + wid * 8 + lr) * (long)K + swc;
    v4i acc[4][4];
    #pragma unroll
    for (int m = 0; m < 4; m++)
        #pragma unroll
        for (int n = 0; n < 4; n++) acc[m][n] = vzero;

    auto STAGE = [&](int buf, int kt) {
        #pragma unroll
        for (int i = 0; i < 4; i++) {
            gload16(ga + kt + (long)(i * 32) * K, &As[buf][(wid * 8 + i * 32) * 128]);
            gload16(gb + kt + (long)(i * 32) * K, &Bs[buf][(wid * 8 + i * 32) * 128]);
        }
    };
    auto COMPUTE = [&](int buf) {
        #pragma unroll
        for (int ks = 0; ks < 2; ks++) {
            v4i af[4], bf[4];
            #pragma unroll
            for (int m = 0; m < 4; m++) {
                int row = wrow + m * 16 + (lane & 15);
                af[m] = *(const v4i*)(&As[buf][row * 128 + (((ks * 4 + (lane >> 4)) ^ (row & 7)) * 16)]);
            }
            #pragma unroll
            for (int n = 0; n < 4; n++) {
                int row = wcol + n * 16 + (lane & 15);
                bf[n] = *(const v4i*)(&Bs[buf][row * 128 + (((ks * 4 + (lane >> 4)) ^ (row & 7)) * 16)]);
            }
            #pragma unroll
            for (int m = 0; m < 4; m++)
                #pragma unroll
                for (int n = 0; n < 4; n++)
                    acc[m][n] = __builtin_amdgcn_mfma_i32_16x16x64_i8(af[m], bf[n], acc[m][n], 0, 0, 0);
        }
    };

    STAGE(0, 0);
    VMCNT0;
    __syncthreads();
    int nt = K >> 7, cur = 0;
    for (int t = 0; t < nt - 1; t++) {
        STAGE(cur ^ 1, (t + 1) << 7);
        COMPUTE(cur);
        VMCNT0;
        __syncthreads();
        cur ^= 1;
    }
    COMPUTE(cur);

    float sA = slot_scale(slots, slotA);
    float sB1s = slot_scale(slots, slotB);
    float sB2s = slot_scale(slots, slotB2);
    int qc = lane & 15, rgrp = (lane >> 4) << 2;
    if (ropemode == 1 || (ropemode == 2 && bn < 8)) {
        __syncthreads();                      // As/Bs dead for all waves
        float* EX = (float*)POOL;             // 128x128 f32; mask (g-based) kills 4-way conflicts
        #pragma unroll
        for (int m = 0; m < 4; m++)
            #pragma unroll
            for (int n = 0; n < 4; n++) {
                int coll = wcol + n * 16 + qc;
                #pragma unroll
                for (int r = 0; r < 4; r++) {
                    int rowl = wrow + m * 16 + rgrp + r;
                    EX[rowl * 128 + (coll ^ (((rowl >> 2) & 3) << 4))] =
                        sA * sB1s * (float)acc[m][n][r];
                }
            }
        __syncthreads();
        float am = 0.f;
        #pragma unroll
        for (int m = 0; m < 4; m++)
            #pragma unroll
            for (int n = 0; n < 4; n++) {
                int coll = wcol + n * 16 + qc;
                #pragma unroll
                for (int r = 0; r < 4; r++) {
                    int rowl = wrow + m * 16 + rgrp + r;
                    int xm = ((rowl >> 2) & 3) << 4;
                    long srow = rowA0 + rowl;
                    float self = EX[rowl * 128 + (coll ^ xm)];
                    float pv = EX[rowl * 128 + ((coll ^ 64) ^ xm)];
                    float c = ct[srow * 64 + (coll & 63)];
                    float sn = st[srow * 64 + (coll & 63)];
                    float o = (coll < 64) ? self * c - pv * sn : self * c + pv * sn;
                    am = fmaxf(am, fabsf(o));
                    Ch[srow * N + colB0 + coll] = __float2half(o);
                }
            }
        block_amax_part(am, (ropemode == 1) ? pQ + blockIdx.x : pK + bm * 8 + (bn & 7));
    } else if (ropemode == 2) {               // V tile: scale + f16 store + absmax
        float am = 0.f;
        #pragma unroll
        for (int m = 0; m < 4; m++) {
            long row0 = rowA0 + wrow + m * 16 + rgrp;
            #pragma unroll
            for (int n = 0; n < 4; n++) {
                int col = (int)colB0 + wcol + n * 16 + qc;
                float sc = sA * ((col < nsplit) ? sB1s : sB2s);
                __half* cp = Ch + row0 * N + col;
                #pragma unroll
                for (int r = 0; r < 4; r++) {
                    float val = sc * (float)acc[m][n][r];
                    cp[(long)r * N] = __float2half(val);
                    am = fmaxf(am, fabsf(val));
                }
            }
        }
        block_amax_part(am, pV + bm * 8 + (bn & 7));
    } else {
        #pragma unroll
        for (int m = 0; m < 4; m++) {
            long row0 = rowA0 + wrow + m * 16 + rgrp;
            #pragma unroll
            for (int n = 0; n < 4; n++) {
                int col = (int)colB0 + wcol + n * 16 + qc;
                float sc = sA * ((col < nsplit) ? sB1s : sB2s);
                float* cp = Cf + row0 * N + col;
                #pragma unroll
                for (int r = 0; r < 4; r++) cp[(long)r * N] = sc * (float)acc[m][n][r];
            }
        }
    }
}

// ---------------- two-pass flash attention (fused-exp softmax, 37.9KB LDS) --------------
__global__ __launch_bounds__(256) void k_attn(
    const int8_t* __restrict__ Qq, const int8_t* __restrict__ Kq, const int8_t* __restrict__ Vtq,
    __half* __restrict__ AO, unsigned* slots) {
    __shared__ int8_t Ks[2][64 * 128];
    __shared__ int8_t Vs[2][128 * 64];   // paired-row swizzled; [0] doubles as Q staging
    __shared__ unsigned Ps[4 * 320];     // packed-P (20-dword stride per warp)
    __shared__ int smx[4];
    const v4i vzero = {0, 0, 0, 0};
    const int NEGS = -(1 << 29);
    const float MAGIC = 12582912.0f;  // 1.5*2^23, RNE rounding
    int tid = threadIdx.x, lane = tid & 63, w = tid >> 6;
    int qlan = lane & 15, g = lane >> 4;
    int idx = blockIdx.x;
    int qb = 31 - (idx >> 5), h = idx & 31, kvh = h >> 2;   // long blocks first
    float sq = slot_scale(slots, 5), sk = slot_scale(slots, 6);
    float spv = slot_scale(slots, 7) * (1.0f / 127.0f);
    float c2 = sq * sk * 0.08838834764831845f * 1.4426950408889634f;
    int lr8 = lane >> 3;
    int swc = ((lane & 7) ^ lr8) * 16;
    const int8_t* kbase = Kq + ((long)(w * 8 + lr8)) * KVDIM + kvh * 128 + swc;
    // V staging: per-thread paired-row inverse source (chunks tid, tid+256)
    int vr0_, vc0_, vr1_, vc1_;
    prsw_inv(tid, vr0_, vc0_);
    prsw_inv(tid + 256, vr1_, vc1_);
    const int8_t* sV0 = Vtq + ((long)kvh * 128 + vr0_) * SEQ + vc0_ * 16;
    const int8_t* sV1 = Vtq + ((long)kvh * 128 + vr1_) * SEQ + vc1_ * 16;
    auto STAGE_K = [&](int buf, int kt) {
        #pragma unroll
        for (int i = 0; i < 2; i++)
            gload16(kbase + ((long)kt * 64 + i * 32) * KVDIM, &Ks[buf][(w * 8 + i * 32) * 128]);
    };
    auto STAGE_V = [&](int buf, int kt) {
        gload16(sV0 + kt * 64, &Vs[buf][w * 1024]);
        gload16(sV1 + kt * 64, &Vs[buf][w * 1024 + 4096]);
    };
    // stage Q (64x128, row&7 XOR layout) into Vs space (dead until pass 2)
    {
        int8_t* Qstage = &Vs[0][0];
        const int8_t* qbase = Qq + ((long)qb * 64 + w * 8 + lr8) * HID + h * 128 + swc;
        #pragma unroll
        for (int i = 0; i < 2; i++)
            gload16(qbase + (long)(i * 32) * HID, &Qstage[(w * 8 + i * 32) * 128]);
    }
    STAGE_K(0, 0);
    VMCNT0;
    __syncthreads();
    v4i aq[2];
    #pragma unroll
    for (int ks = 0; ks < 2; ks++) {
        int row = w * 16 + qlan;
        aq[ks] = *(const v4i*)(&Vs[0][row * 128 + (((ks * 4 + g) ^ (row & 7)) * 16)]);
    }
    __syncthreads();   // all aq reads done before Vs reuse
    int mi = -(1 << 30);
    float l = 0.f;
    int buf = 0;
    // ---- pass 1: int row-max + fused-exp denominator ----
    for (int kt = 0; kt <= qb; kt++) {
        if (kt < qb) STAGE_K(buf ^ 1, kt + 1);
        v4i sf[4] = {vzero, vzero, vzero, vzero};
        __builtin_amdgcn_s_setprio(1);
        #pragma unroll
        for (int ks = 0; ks < 2; ks++)
            #pragma unroll
            for (int f = 0; f < 4; f++) {
                int row = f * 16 + qlan;
                v4i bk = *(const v4i*)(&Ks[buf][row * 128 + (((ks * 4 + g) ^ (row & 7)) * 16)]);
                sf[f] = __builtin_amdgcn_mfma_i32_16x16x64_i8(bk, aq[ks], sf[f], 0, 0, 0);
            }
        __builtin_amdgcn_s_setprio(0);
        int sv[16];
        if (kt == qb) {
            int qthr = w * 16 + qlan;
            #pragma unroll
            for (int f = 0; f < 4; f++)
                #pragma unroll
                for (int r = 0; r < 4; r++) {
                    int kl = f * 16 + g * 4 + r;
                    sv[f * 4 + r] = (kl > qthr) ? NEGS : sf[f][r];
                }
        } else {
            #pragma unroll
            for (int f = 0; f < 4; f++)
                #pragma unroll
                for (int r = 0; r < 4; r++) sv[f * 4 + r] = sf[f][r];
        }
        int tm = sv[0];
        #pragma unroll
        for (int e = 1; e < 16; e++) tm = tm > sv[e] ? tm : sv[e];
        tm = max(tm, __shfl_xor(tm, 16, 64));
        tm = max(tm, __shfl_xor(tm, 32, 64));
        int mn = tm > mi ? tm : mi;
        float nb = -c2 * (float)mn;
        float esc = fexp2(fmaf((float)mi, c2, nb));
        float es = 0.f;
        #pragma unroll
        for (int e = 0; e < 16; e++) es += fexp2(fmaf((float)sv[e], c2, nb));
        es += __shfl_xor(es, 16, 64);
        es += __shfl_xor(es, 32, 64);
        l = l * esc + es;
        mi = mn;
        VMCNT0;
        __syncthreads();
        buf ^= 1;
    }
    // fused quant bias: p_q127 = exp2(c2*s - Bq), Bq = c2*m + log2(l) - log2(127)
    float Bq = fmaf(c2, (float)mi, __log2f(l) - 6.9886846867721655f);
    // ---- pass 2 ----
    int pwr = w * 320;
    v4i of[8];
    #pragma unroll
    for (int nf = 0; nf < 8; nf++) of[nf] = vzero;
    STAGE_K(0, 0);
    STAGE_V(0, 0);
    VMCNT0;
    __syncthreads();
    buf = 0;
    for (int kt = 0; kt <= qb; kt++) {
        if (kt < qb) { STAGE_K(buf ^ 1, kt + 1); STAGE_V(buf ^ 1, kt + 1); }
        v4i sf[4] = {vzero, vzero, vzero, vzero};
        __builtin_amdgcn_s_setprio(1);
        #pragma unroll
        for (int ks = 0; ks < 2; ks++)
            #pragma unroll
            for (int f = 0; f < 4; f++) {
                int row = f * 16 + qlan;
                v4i bk = *(const v4i*)(&Ks[buf][row * 128 + (((ks * 4 + g) ^ (row & 7)) * 16)]);
                sf[f] = __builtin_amdgcn_mfma_i32_16x16x64_i8(bk, aq[ks], sf[f], 0, 0, 0);
            }
        __builtin_amdgcn_s_setprio(0);
        if (kt == qb) {
            int qthr = w * 16 + qlan;
            #pragma unroll
            for (int f = 0; f < 4; f++) {
                unsigned pk = 0;
                #pragma unroll
                for (int r = 0; r < 4; r++) {
                    int kl = f * 16 + g * 4 + r;
                    int s = (kl > qthr) ? NEGS : sf[f][r];
                    float t = fexp2(fmaf((float)s, c2, -Bq));
                    unsigned u = __float_as_uint(t + MAGIC) & 127u;
                    pk |= u << (8 * r);
                }
                Ps[pwr + (4 * f + g) * 20 + qlan] = pk;
            }
        } else {
            #pragma unroll
            for (int f = 0; f < 4; f++) {
                unsigned pk = 0;
                #pragma unroll
                for (int r = 0; r < 4; r++) {
                    float t = fexp2(fmaf((float)sf[f][r], c2, -Bq));
                    unsigned u = __float_as_uint(t + MAGIC) & 127u;
                    pk |= u << (8 * r);
                }
                Ps[pwr + (4 * f + g) * 20 + qlan] = pk;
            }
        }
        int rb = pwr + 80 * g + qlan;
        v4i ap;
        ap[0] = (int)Ps[rb];
        ap[1] = (int)Ps[rb + 20];
        ap[2] = (int)Ps[rb + 40];
        ap[3] = (int)Ps[rb + 60];
        __builtin_amdgcn_s_setprio(1);
        #pragma unroll
        for (int nf = 0; nf < 8; nf++) {
            int row = nf * 16 + qlan;
            v4i bv = *(const v4i*)(&Vs[buf][prsw(row, g) * 16]);
            of[nf] = __builtin_amdgcn_mfma_i32_16x16x64_i8(ap, bv, of[nf], 0, 0, 0);
        }
        __builtin_amdgcn_s_setprio(0);
        VMCNT0;
        __syncthreads();
        buf ^= 1;
    }
    int mymax = 0;
    #pragma unroll
    for (int nf = 0; nf < 8; nf++)
        #pragma unroll
        for (int r = 0; r < 4; r++) {
            int val = of[nf][r];
            int av = val < 0 ? -val : val;
            mymax = av > mymax ? av : mymax;
            int qg = qb * 64 + w * 16 + 4 * g + r;
            AO[(long)qg * HID + h * 128 + nf * 16 + qlan] = __float2half(spv * (float)val);
        }
    #pragma unroll
    for (int off = 1; off < 64; off <<= 1) {
        int o2 = __shfl_xor(mymax, off, 64);
        mymax = o2 > mymax ? o2 : mymax;
    }
    if (lane == 0) smx[w] = mymax;
    __syncthreads();
    if (tid == 0) {
        int mm = max(max(smx[0], smx[1]), max(smx[2], smx[3]));
        atomicMax(slots + (8 << 5), (unsigned)mm);   // staggered retirement
    }
}

// ---------------- quantize attn_out (f16 -> int8), packed ----------------
__global__ void k_quant_ao(const __half* __restrict__ a, int8_t* __restrict__ q,
                           unsigned* slots) {
    float sv = slot_scale(slots, 7);
    float spv = (1.0f / 127.0f) * sv;
    float amax = spv * (float)(int)slots[8 << 5];
    float s = fmaxf(amax / 127.0f, 1e-8f);
    long nu = (long)SEQ * HID / 16;
    long gs = (long)gridDim.x * blockDim.x;
    for (long u = blockIdx.x * (long)blockDim.x + threadIdx.x; u < nu; u += gs) {
        const int4* src = (const int4*)(a + u * 16);
        int4 x = src[0], y = src[1];
        int4 o;
        o.x = (int)pk4h((unsigned)x.x, (unsigned)x.y, s);
        o.y = (int)pk4h((unsigned)x.z, (unsigned)x.w, s);
        o.z = (int)pk4h((unsigned)y.x, (unsigned)y.y, s);
        o.w = (int)pk4h((unsigned)y.z, (unsigned)y.w, s);
        *(int4*)(q + u * 16) = o;
    }
    if (blockIdx.x == 0 && threadIdx.x == 0) slots[9 << 5] = __float_as_uint(amax);
}

extern "C" void kernel_launch(void* const* d_in, const int* in_sizes, int n_in,
                              void* d_out, int out_size, void* d_ws, size_t ws_size,
                              hipStream_t stream) {
    (void)in_sizes; (void)n_in; (void)out_size;
    const float* hid = (const float*)d_in[0];
    const int* pos = (const int*)d_in[2];
    const float* wqp = (const float*)d_in[3];
    const float* wkp = (const float*)d_in[4];
    const float* wvp = (const float*)d_in[5];
    const float* wop = (const float*)d_in[6];
    float* out = (float*)d_out;
    char* ws = (char*)d_ws;

    size_t o = 0;
    auto alloc = [&](size_t sz) { size_t r = o; o += (sz + 255) & ~(size_t)255; return r; };
    unsigned* slots = (unsigned*)(ws + alloc(2048));
    float* P0 = (float*)(ws + alloc(2048 * 4));      // absmax5 partials
    float* P1 = (float*)(ws + alloc(512 * 4));       // gemm1 Q-rope partials
    float* P2 = (float*)(ws + alloc(128 * 4));       // gemm2 K-rope partials
    float* P3 = (float*)(ws + alloc(128 * 4));       // gemm2 V partials
    int8_t* Xq   = (int8_t*)(ws + alloc((size_t)SEQ * HID));      // later reused as AOq
    int8_t* Wqq  = (int8_t*)(ws + alloc((size_t)HID * HID));
    int8_t* Woq  = (int8_t*)(ws + alloc((size_t)HID * HID));
    int8_t* Wkvq = (int8_t*)(ws + alloc((size_t)KVCAT * HID));
    __half* Qf   = (__half*)(ws + alloc((size_t)SEQ * HID * 2));  // later reused as AOh
    __half* KVf  = (__half*)(ws + alloc((size_t)SEQ * KVCAT * 2));
    int8_t* Qq   = (int8_t*)(ws + alloc((size_t)SEQ * HID));
    int8_t* Kq   = (int8_t*)(ws + alloc((size_t)SEQ * KVDIM));
    int8_t* Vtq  = (int8_t*)(ws + alloc((size_t)KVDIM * SEQ));
    float*  ctab = (float*)(ws + alloc((size_t)SEQ * 64 * 4));
    float*  stab = (float*)(ws + alloc((size_t)SEQ * 64 * 4));
    if (ws_size < o) return;
    __half* AOh = Qf;
    int8_t* AOq = Xq;

    (void)hipMemsetAsync(slots, 0, 2048, stream);
    k_ropetab<<<SEQ * 64 / 256, 256, 0, stream>>>(pos, ctab, stab);
    k_absmax5<<<2048, 256, 0, stream>>>(hid, wqp, wkp, wvp, wop, P0);
    k_reduceA<<<1, 256, 0, stream>>>(P0, slots);
    k_quant5<<<3072, 256, 0, stream>>>(hid, wqp, wkp, wvp, wop,
                                       Xq, Wqq, Wkvq, Wkvq + (size_t)KVDIM * HID, Woq, slots);
    k_gemm_i8<<<512, 256, 0, stream>>>(Xq, Wqq, Qf, HID, HID, slots,
                                       0, 1, 1, 1 << 30, P1, nullptr, nullptr, 1, ctab, stab);
    k_gemm_i8<<<256, 256, 0, stream>>>(Xq, Wkvq, KVf, KVCAT, HID, slots,
                                       0, 2, 3, KVDIM, nullptr, P2, P3, 2, ctab, stab);
    k_reduceB<<<1, 256, 0, stream>>>(P1, P2, P3, slots);
    const long CALL = 0x3FFFFFFFL;
    k_quanth<<<1024, 256, 0, stream>>>(Qf, Qq, (long)SEQ * HID / 16, 40, CALL, 0, slots, 5);
    k_quanth<<<512, 256, 0, stream>>>(KVf, Kq, (long)SEQ * KVDIM / 16, 6, 63, KVCAT, slots, 6);
    k_transq<<<dim3(32, 64), 256, 0, stream>>>(KVf + KVDIM, KVCAT, Vtq, SEQ, slots, 7);
    k_attn<<<1024, 256, 0, stream>>>(Qq, Kq, Vtq, AOh, slots);
    k_quant_ao<<<1024, 256, 0, stream>>>(AOh, AOq, slots);
    k_gemm_i8<<<512, 256, 0, stream>>>(AOq, Woq, out, HID, HID, slots,
                                       9, 4, 4, 1 << 30, nullptr, nullptr, nullptr, 0,
                                       nullptr, nullptr);
}